// Round 8
// baseline (1570.976 us; speedup 1.0000x reference)
//
#include <hip/hip_runtime.h>
#include <cstdint>
#include <cstdio>

// ---------------- device helpers ----------------

struct Coords { int xi, yi, zi; };

// EXACT replication of reference quantization (all f32 ops, truncating cast)
__device__ __forceinline__ Coords quantc(float x, float y, float z, float sx, float sy, float sz) {
    Coords c;
    c.xi = (int)(((x - 0.0f)  / 51.2f) * sx);
    c.yi = (int)(((y + 25.6f) / 51.2f) * sy);
    c.zi = (int)(((z + 2.0f)  / 6.4f)  * sz);
    return c;
}

__device__ __forceinline__ int batch_of(int i, const int* __restrict__ ind, int B) {
    int bt = 0;
    for (int b = 1; b < B; ++b) if (i >= ind[b]) bt = b;
    return bt;
}

// order-preserving float<->uint transform for atomicMax on signed floats
__device__ __forceinline__ unsigned f2o(float f) {
    unsigned u = __float_as_uint(f);
    return (u & 0x80000000u) ? ~u : (u | 0x80000000u);
}
__device__ __forceinline__ float o2f(unsigned u) {
    return (u & 0x80000000u) ? __uint_as_float(u ^ 0x80000000u) : __uint_as_float(~u);
}
#define NEG_O 0x007FFFFFu   // f2o(-inf)

// bf16 helpers (RTNE)
__device__ __forceinline__ unsigned short f2bf(float x) {
    unsigned u = __float_as_uint(x);
    unsigned r = (u + 0x7FFFu + ((u >> 16) & 1u)) >> 16;
    return (unsigned short)r;
}
__device__ __forceinline__ float bf2f(unsigned h) {
    return __uint_as_float(h << 16);
}

// x[16] = (feat@W.T + b) * (mean@Ww.T + wb);  mean6 out = [mm, gmm]
__device__ __forceinline__ void compute_x16(
    float px, float py, float pz, float pw,
    float mx_, float my_, float mz_, Coords c,
    const float* __restrict__ W, const float* __restrict__ Bv,
    const float* __restrict__ Ww, const float* __restrict__ Wb,
    float* __restrict__ x, float* __restrict__ mean6) {
    float gx = px - (((float)c.xi + 0.5f) * 0.2f + 0.0f);
    float gy = py - (((float)c.yi + 0.5f) * 0.2f + (-25.6f));
    float gz = pz - (((float)c.zi + 0.5f) * 0.2f + (-2.0f));
    float mmx = px - mx_, mmy = py - my_, mmz = pz - mz_;
    float feat[10] = {px, py, pz, pw, mmx, mmy, mmz, gx, gy, gz};
    float mean[6]  = {mmx, mmy, mmz, gx, gy, gz};
#pragma unroll
    for (int j = 0; j < 6; ++j) mean6[j] = mean[j];
#pragma unroll
    for (int o = 0; o < 16; ++o) {
        float a = Bv[o];
#pragma unroll
        for (int j = 0; j < 10; ++j) a += feat[j] * W[o * 10 + j];
        float g = Wb[o];
#pragma unroll
        for (int j = 0; j < 6; ++j) g += mean[j] * Ww[o * 6 + j];
        x[o] = a * g;
    }
}

// ---------------- bitmask unique-rank machinery ----------------

__global__ __launch_bounds__(256) void k_bits(
    const float4* __restrict__ pc, const int* __restrict__ ind, int B, int n,
    unsigned* __restrict__ mask05, unsigned* __restrict__ mask1) {
    int i = blockIdx.x * 256 + threadIdx.x;
    if (i >= n) return;
    float4 p = pc[i];
    int bt = batch_of(i, ind, B);
    Coords c05 = quantc(p.x, p.y, p.z, 512.f, 512.f, 64.f);
    Coords c1  = quantc(p.x, p.y, p.z, 256.f, 256.f, 32.f);
    int lid05 = ((bt * 512 + c05.xi) * 512 + c05.yi) * 64 + c05.zi;
    int lid1  = ((bt * 256 + c1.xi)  * 256 + c1.yi)  * 32 + c1.zi;
    atomicOr(&mask05[lid05 >> 5], 1u << (lid05 & 31));
    atomicOr(&mask1[lid1 >> 5],  1u << (lid1 & 31));
}

// merged popc-chunk over BOTH masks (blockIdx split)
__global__ __launch_bounds__(256) void k_chunk2(
    const unsigned* __restrict__ maskA, unsigned* __restrict__ bsumA, int nWA, int nBA,
    const unsigned* __restrict__ maskB, unsigned* __restrict__ bsumB, int nWB) {
    const unsigned* mask; unsigned* bsum; int nW, blk;
    if ((int)blockIdx.x < nBA) { mask = maskA; bsum = bsumA; nW = nWA; blk = blockIdx.x; }
    else { mask = maskB; bsum = bsumB; nW = nWB; blk = blockIdx.x - nBA; }
    int t = threadIdx.x;
    int base = blk * 2048 + t;
    unsigned tot = 0;
#pragma unroll
    for (int k = 0; k < 8; ++k) {
        int w = base + k * 256;
        if (w < nW) tot += __popc(mask[w]);
    }
    __shared__ unsigned s[256];
    s[t] = tot;
    __syncthreads();
    for (int off = 128; off > 0; off >>= 1) {
        if (t < off) s[t] += s[t + off];
        __syncthreads();
    }
    if (t == 0) bsum[blk] = s[0];
}

// merged chunk-sum over both cnt arrays
__global__ __launch_bounds__(256) void k_chunku2(
    const unsigned* __restrict__ cntA, unsigned* __restrict__ bsumA,
    const unsigned* __restrict__ cntB, unsigned* __restrict__ bsumB,
    int nElem, int nCh) {
    const unsigned* val; unsigned* bsum; int blk;
    if ((int)blockIdx.x < nCh) { val = cntA; bsum = bsumA; blk = blockIdx.x; }
    else { val = cntB; bsum = bsumB; blk = blockIdx.x - nCh; }
    int t = threadIdx.x;
    int base = blk * 2048 + t;
    unsigned tot = 0;
#pragma unroll
    for (int k = 0; k < 8; ++k) {
        int w = base + k * 256;
        if (w < nElem) tot += val[w];
    }
    __shared__ unsigned s[256];
    s[t] = tot;
    __syncthreads();
    for (int off = 128; off > 0; off >>= 1) {
        if (t < off) s[t] += s[t + off];
        __syncthreads();
    }
    if (t == 0) bsum[blk] = s[0];
}

// merged single-block scans: block 0 does set A, block 1 set B
__global__ __launch_bounds__(1024) void k_scan2(
    const unsigned* __restrict__ bsumA, unsigned* __restrict__ bprefA,
    unsigned* __restrict__ UoutA, int nA,
    const unsigned* __restrict__ bsumB, unsigned* __restrict__ bprefB,
    unsigned* __restrict__ UoutB, int nB) {
    const unsigned* bsum; unsigned* bpref; unsigned* Uout; int nBn;
    if (blockIdx.x == 0) { bsum = bsumA; bpref = bprefA; Uout = UoutA; nBn = nA; }
    else { bsum = bsumB; bpref = bprefB; Uout = UoutB; nBn = nB; }
    __shared__ unsigned s[1024];
    int t = threadIdx.x;
    int ipt = (nBn + 1023) >> 10;
    unsigned tot = 0;
    for (int k = 0; k < ipt; ++k) {
        int e = t * ipt + k;
        if (e < nBn) tot += bsum[e];
    }
    s[t] = tot;
    __syncthreads();
    for (int off = 1; off < 1024; off <<= 1) {
        unsigned v = 0;
        if (t >= off) v = s[t - off];
        __syncthreads();
        if (t >= off) s[t] += v;
        __syncthreads();
    }
    unsigned run = s[t] - tot;  // exclusive
    for (int k = 0; k < ipt; ++k) {
        int e = t * ipt + k;
        if (e < nBn) { bpref[e] = run; run += bsum[e]; }
    }
    if (t == 1023 && Uout) *Uout = s[1023];
}

// merged per-word prefix over both masks
__global__ __launch_bounds__(256) void k_wpref2(
    const unsigned* __restrict__ maskA, const unsigned* __restrict__ bprefA,
    unsigned* __restrict__ wprefA, int nWA, int nBA,
    const unsigned* __restrict__ maskB, const unsigned* __restrict__ bprefB,
    unsigned* __restrict__ wprefB, int nWB) {
    const unsigned* mask; const unsigned* bpref; unsigned* wpref; int nW, blk;
    if ((int)blockIdx.x < nBA) { mask = maskA; bpref = bprefA; wpref = wprefA; nW = nWA; blk = blockIdx.x; }
    else { mask = maskB; bpref = bprefB; wpref = wprefB; nW = nWB; blk = blockIdx.x - nBA; }
    int t = threadIdx.x;
    int base = blk * 2048 + t * 8;
    unsigned p[8];
    unsigned tot = 0;
#pragma unroll
    for (int k = 0; k < 8; ++k) {
        int w = base + k;
        p[k] = (w < nW) ? __popc(mask[w]) : 0u;
        tot += p[k];
    }
    __shared__ unsigned s[256];
    s[t] = tot;
    __syncthreads();
    for (int off = 1; off < 256; off <<= 1) {
        unsigned v = 0;
        if (t >= off) v = s[t - off];
        __syncthreads();
        if (t >= off) s[t] += v;
        __syncthreads();
    }
    unsigned run = bpref[blk] + (s[t] - tot);
#pragma unroll
    for (int k = 0; k < 8; ++k) {
        int w = base + k;
        if (w < nW) { wpref[w] = run; run += p[k]; }
    }
}

// merged element prefix over both cnt arrays -> start offsets
__global__ __launch_bounds__(256) void k_eprefu2(
    const unsigned* __restrict__ cntA, const unsigned* __restrict__ bprefA,
    unsigned* __restrict__ startA,
    const unsigned* __restrict__ cntB, const unsigned* __restrict__ bprefB,
    unsigned* __restrict__ startB,
    int nElem, int nCh) {
    const unsigned* val; const unsigned* bpref; unsigned* epref; int blk;
    if ((int)blockIdx.x < nCh) { val = cntA; bpref = bprefA; epref = startA; blk = blockIdx.x; }
    else { val = cntB; bpref = bprefB; epref = startB; blk = blockIdx.x - nCh; }
    int t = threadIdx.x;
    int base = blk * 2048 + t * 8;
    unsigned p[8];
    unsigned tot = 0;
#pragma unroll
    for (int k = 0; k < 8; ++k) {
        int w = base + k;
        p[k] = (w < nElem) ? val[w] : 0u;
        tot += p[k];
    }
    __shared__ unsigned s[256];
    s[t] = tot;
    __syncthreads();
    for (int off = 1; off < 256; off <<= 1) {
        unsigned v = 0;
        if (t >= off) v = s[t - off];
        __syncthreads();
        if (t >= off) s[t] += v;
        __syncthreads();
    }
    unsigned run = bpref[blk] + (s[t] - tot);
#pragma unroll
    for (int k = 0; k < 8; ++k) {
        int w = base + k;
        if (w < nElem) { epref[w] = run; run += p[k]; }
    }
}

// ---------------- point passes ----------------

// ranks + counts + slots. ONE scattered atomic per point per scale — the
// atomicAdd's return value IS the slot. outCoord written once per voxel.
__global__ __launch_bounds__(256) void k_rank(
    const float4* __restrict__ pc, const int* __restrict__ ind, int B, int n,
    const unsigned* __restrict__ mask05, const unsigned* __restrict__ wp05,
    const unsigned* __restrict__ mask1, const unsigned* __restrict__ wp1,
    unsigned* __restrict__ inv05, unsigned* __restrict__ inv1,
    unsigned* __restrict__ cnt05, unsigned* __restrict__ cnt1,
    unsigned* __restrict__ slot05, unsigned* __restrict__ slot1,
    float* __restrict__ outCoord, float* __restrict__ outInv) {
    int i = blockIdx.x * 256 + threadIdx.x;
    if (i >= n) return;
    float4 p = pc[i];
    int bt = batch_of(i, ind, B);
    Coords c05 = quantc(p.x, p.y, p.z, 512.f, 512.f, 64.f);
    Coords c1  = quantc(p.x, p.y, p.z, 256.f, 256.f, 32.f);
    int lid05 = ((bt * 512 + c05.xi) * 512 + c05.yi) * 64 + c05.zi;
    int lid1  = ((bt * 256 + c1.xi)  * 256 + c1.yi)  * 32 + c1.zi;

    unsigned w = (unsigned)lid05 >> 5, b = (unsigned)lid05 & 31u;
    unsigned r05 = wp05[w] + __popc(mask05[w] & ((1u << b) - 1u));
    w = (unsigned)lid1 >> 5; b = (unsigned)lid1 & 31u;
    unsigned r1 = wp1[w] + __popc(mask1[w] & ((1u << b) - 1u));

    inv05[i] = r05;
    inv1[i] = r1;
    outInv[i] = (float)r1;

    slot05[i] = atomicAdd(&cnt05[r05], 1u);
    unsigned sl1 = atomicAdd(&cnt1[r1], 1u);
    slot1[i] = sl1;
    if (sl1 == 0u)
        ((float4*)outCoord)[r1] = make_float4((float)bt, (float)c1.xi, (float)c1.yi, (float)c1.zi);
}

// counting-sort scatter of 32B point records into CSR order.
// recA05[2j]={p}, recA05[2j+1]={r05,-,-,-}
// recA1 [2j]={p}, recA1 [2j+1]={r1, r05, meta,-}; meta = start1 | min(cnt1,257)<<23
__global__ __launch_bounds__(256) void k_slot(
    const float4* __restrict__ pc,
    const unsigned* __restrict__ inv05, const unsigned* __restrict__ inv1,
    const unsigned* __restrict__ slot05, const unsigned* __restrict__ slot1,
    const unsigned* __restrict__ start05, const unsigned* __restrict__ start1,
    const unsigned* __restrict__ cnt1,
    uint4* __restrict__ recA05, uint4* __restrict__ recA1, int n) {
    int i = blockIdx.x * 256 + threadIdx.x;
    if (i >= n) return;
    float4 p = pc[i];
    unsigned r05 = inv05[i], r1 = inv1[i];
    unsigned p05 = start05[r05] + slot05[i];
    unsigned s1 = start1[r1];
    unsigned p1  = s1 + slot1[i];
    unsigned c1 = cnt1[r1];
    unsigned cm = c1 < 257u ? c1 : 257u;
    unsigned meta = s1 | (cm << 23);
    uint4 pw = *(const uint4*)&p;
    recA05[(size_t)p05 * 2]     = pw;
    recA05[(size_t)p05 * 2 + 1] = make_uint4(r05, 0u, 0u, 0u);
    recA1[(size_t)p1 * 2]       = pw;
    recA1[(size_t)p1 * 2 + 1]   = make_uint4(r1, r05, meta, 0u);
}

// merged: wave-level segmented mean over CSR records for BOTH scales, plus the
// boundary-flag/binit pass as a third blockIdx range. Points read coalesced.
__global__ __launch_bounds__(256) void k_segmean2(
    const uint4* __restrict__ recA05, const unsigned* __restrict__ start05,
    const unsigned* __restrict__ cnt05, float4* __restrict__ mean05,
    const uint4* __restrict__ recA1, const unsigned* __restrict__ start1,
    const unsigned* __restrict__ cnt1, float4* __restrict__ mean1,
    unsigned char* __restrict__ flags, unsigned* __restrict__ outMaxU,
    int n, int gpts) {
    // third range: boundary-segment flags + atomicMax row init
    if ((int)blockIdx.x >= 2 * gpts) {
        int blk3 = blockIdx.x - 2 * gpts;
        int b = blk3 * 256 + threadIdx.x + 1;
        if (b >= gpts) return;
        int j = b * 256;
        if (j >= n) return;
        unsigned r = recA1[(size_t)j * 2 + 1].x;
        if (start1[r] < (unsigned)j) {
            flags[r] = 1;
            unsigned* row = outMaxU + (size_t)r * 32;
#pragma unroll
            for (int o = 0; o < 32; ++o) row[o] = NEG_O;
        }
        return;
    }
    const uint4* recA; const unsigned* start; const unsigned* cnt;
    float4* meanOut; int blk;
    if ((int)blockIdx.x < gpts) {
        recA = recA05; start = start05; cnt = cnt05; meanOut = mean05; blk = blockIdx.x;
    } else {
        recA = recA1; start = start1; cnt = cnt1; meanOut = mean1; blk = blockIdx.x - gpts;
    }
    int j = blk * 256 + threadIdx.x;
    int lane = threadIdx.x & 63;
    bool live = j < n;
    unsigned r = 0xFFFFFFFFu;
    float sx = 0.f, sy = 0.f, sz = 0.f;
    if (live) {
        float4 p = *(const float4*)&recA[(size_t)j * 2];
        r = recA[(size_t)j * 2 + 1].x;
        sx = p.x; sy = p.y; sz = p.z;
    }
#pragma unroll
    for (int d = 1; d < 64; d <<= 1) {
        unsigned rn = (unsigned)__shfl_down((int)r, d);
        float ax = __shfl_down(sx, d);
        float ay = __shfl_down(sy, d);
        float az = __shfl_down(sz, d);
        bool ok = (lane + d) < 64 && rn == r;
        if (ok) { sx += ax; sy += ay; sz += az; }
    }
    if (!live) return;
    if (j != (int)start[r]) return;
    unsigned c = cnt[r];
    unsigned end = j + c;
    unsigned waveEnd = ((unsigned)j & ~63u) + 64u;
    for (unsigned j2 = waveEnd; j2 < end; ++j2) {
        float4 q = *(const float4*)&recA[(size_t)j2 * 2];
        sx += q.x; sy += q.y; sz += q.z;
    }
    float cf = (float)c;
    meanOut[r] = make_float4(sx / cf, sy / cf, sz / cf, 0.f);
}

// merged block-level LDS segmented max of x16 for BOTH scales (blockIdx split).
// VFE weights staged in LDS (288+32 dwords) — broadcast ds_reads, no per-point
// cache reload.
__global__ __launch_bounds__(256) void k_segmx2(
    const uint4* __restrict__ recA05, const unsigned* __restrict__ start05,
    const unsigned* __restrict__ cnt05, const float4* __restrict__ mean05,
    const float* __restrict__ w05, const float* __restrict__ b05,
    const float* __restrict__ ww05, const float* __restrict__ wb05,
    unsigned short* __restrict__ mx05,
    const uint4* __restrict__ recA1, const unsigned* __restrict__ start1,
    const unsigned* __restrict__ cnt1, const float4* __restrict__ mean1,
    const float* __restrict__ w1, const float* __restrict__ b1,
    const float* __restrict__ ww1, const float* __restrict__ wb1,
    unsigned short* __restrict__ mx1,
    int n, int gpts) {
    const uint4* recA; const unsigned* start; const unsigned* cnt;
    const float4* meanIn; const float* W; const float* Bv; const float* Ww;
    const float* Wb; unsigned short* mxOut; int blk;
    float sx_, sy_, sz_;
    if ((int)blockIdx.x < gpts) {
        recA = recA05; start = start05; cnt = cnt05; meanIn = mean05;
        W = w05; Bv = b05; Ww = ww05; Wb = wb05; mxOut = mx05;
        sx_ = 512.f; sy_ = 512.f; sz_ = 64.f; blk = blockIdx.x;
    } else {
        recA = recA1; start = start1; cnt = cnt1; meanIn = mean1;
        W = w1; Bv = b1; Ww = ww1; Wb = wb1; mxOut = mx1;
        sx_ = 256.f; sy_ = 256.f; sz_ = 32.f; blk = blockIdx.x - gpts;
    }
    __shared__ float buf[256][17];
    __shared__ float sWm[288];   // W 0..160 | Bv 160 | Ww 176..272 | Wb 272
    int t = threadIdx.x;
    for (int i2 = t; i2 < 160; i2 += 256) sWm[i2] = W[i2];
    for (int i2 = t; i2 < 96; i2 += 256) sWm[176 + i2] = Ww[i2];
    if (t < 16) { sWm[160 + t] = Bv[t]; sWm[272 + t] = Wb[t]; }
    __syncthreads();
    int j = blk * 256 + t;
    bool live = j < n;
    unsigned r = 0;
    float x[16], d6[6];
    if (live) {
        float4 p = *(const float4*)&recA[(size_t)j * 2];
        r = recA[(size_t)j * 2 + 1].x;
        float4 mv = meanIn[r];
        Coords cc = quantc(p.x, p.y, p.z, sx_, sy_, sz_);
        compute_x16(p.x, p.y, p.z, p.w, mv.x, mv.y, mv.z, cc,
                    sWm, sWm + 160, sWm + 176, sWm + 272, x, d6);
    } else {
#pragma unroll
        for (int o = 0; o < 16; ++o) x[o] = 0.f;
    }
#pragma unroll
    for (int o = 0; o < 16; ++o) buf[t][o] = x[o];
    __syncthreads();
    if (!live || j != (int)start[r]) return;
    unsigned c = cnt[r];
    unsigned end = j + c;
    unsigned blockEnd = ((unsigned)blk + 1u) * 256u;
    unsigned inEnd = end < blockEnd ? end : blockEnd;
    for (unsigned j2 = j + 1; j2 < inEnd; ++j2) {
        int t2 = t + (int)(j2 - (unsigned)j);
#pragma unroll
        for (int o = 0; o < 16; ++o) x[o] = fmaxf(x[o], buf[t2][o]);
    }
    float4 mv = meanIn[r];
    for (unsigned j2 = blockEnd; j2 < end; ++j2) {
        float4 q = *(const float4*)&recA[(size_t)j2 * 2];
        Coords cc = quantc(q.x, q.y, q.z, sx_, sy_, sz_);
        float x2[16];
        compute_x16(q.x, q.y, q.z, q.w, mv.x, mv.y, mv.z, cc,
                    sWm, sWm + 160, sWm + 176, sWm + 272, x2, d6);
#pragma unroll
        for (int o = 0; o < 16; ++o) x[o] = fmaxf(x[o], x2[o]);
    }
    unsigned pk[8];
#pragma unroll
    for (int k = 0; k < 8; ++k)
        pk[k] = (unsigned)f2bf(x[2 * k]) | ((unsigned)f2bf(x[2 * k + 1]) << 16);
    uint4* mr = (uint4*)(mxOut + (size_t)r * 16);
    mr[0] = make_uint4(pk[0], pk[1], pk[2], pk[3]);
    mr[1] = make_uint4(pk[4], pk[5], pk[6], pk[7]);
}

// sW packed layout (dword offsets) for k_val weight staging
#define O_ATW 0      // 2048: at_w [32][64]
#define O_AFW 2048   // 1024: af_w [32][32]
#define O_W05 3072   // 160
#define O_WW05 3232  // 96
#define O_W1 3328    // 160
#define O_WW1 3488   // 96
#define O_AMW 3584   // 192
#define O_ATB 3776   // 32
#define O_AFB 3808   // 32
#define O_B05 3840   // 16
#define O_WB05 3856  // 16
#define O_B1 3872    // 16
#define O_WB1 3888   // 16
#define O_AMB 3904   // 32
#define SW_TOTAL 3936

// fused per-point pipeline + two-phase in-block segmented max.
// ALL weights (3936 dwords, 15.7 KB) staged once per block into LDS —
// every inner-loop weight read is a same-address LDS broadcast instead of a
// per-point L1/SMEM reload (round-7 diagnosis: ~250 uniform weight-load
// batches/wave x ~200cyc was the k_val critical path, not FMAs or gathers).
// (256,3): round-4 lesson — tighter caps spill at[32] to scratch.
__global__ __launch_bounds__(256, 3) void k_val(
    const uint4* __restrict__ recA1,
    const float4* __restrict__ mean05, const unsigned short* __restrict__ mx05,
    const float4* __restrict__ mean1, const unsigned short* __restrict__ mx1,
    const float* __restrict__ w05, const float* __restrict__ b05,
    const float* __restrict__ ww05, const float* __restrict__ wb05,
    const float* __restrict__ w1g, const float* __restrict__ b1g,
    const float* __restrict__ ww1, const float* __restrict__ wb1,
    const float* __restrict__ am_w, const float* __restrict__ am_b,
    const float* __restrict__ at_w, const float* __restrict__ at_b,
    const float* __restrict__ af_w, const float* __restrict__ af_b,
    float* __restrict__ outMax, int n) {
    __shared__ float buf[256][17];
    __shared__ float sW[SW_TOTAL];
    int t = threadIdx.x;
    // ---- stage all weights (coalesced, once per block) ----
    for (int i2 = t; i2 < 2048; i2 += 256) sW[O_ATW + i2] = at_w[i2];
    for (int i2 = t; i2 < 1024; i2 += 256) sW[O_AFW + i2] = af_w[i2];
    for (int i2 = t; i2 < 160; i2 += 256) sW[O_W05 + i2] = w05[i2];
    for (int i2 = t; i2 < 96; i2 += 256) sW[O_WW05 + i2] = ww05[i2];
    for (int i2 = t; i2 < 160; i2 += 256) sW[O_W1 + i2] = w1g[i2];
    for (int i2 = t; i2 < 96; i2 += 256) sW[O_WW1 + i2] = ww1[i2];
    for (int i2 = t; i2 < 192; i2 += 256) sW[O_AMW + i2] = am_w[i2];
    if (t < 32) { sW[O_ATB + t] = at_b[t]; sW[O_AFB + t] = af_b[t]; sW[O_AMB + t] = am_b[t]; }
    if (t < 16) {
        sW[O_B05 + t] = b05[t]; sW[O_WB05 + t] = wb05[t];
        sW[O_B1 + t] = b1g[t]; sW[O_WB1 + t] = wb1[t];
    }
    __syncthreads();

    int j = blockIdx.x * 256 + t;
    bool live = j < n;
    unsigned r = 0, s = 0, c = 0;
    bool bound = false;
    float at[32];
    if (live) {
        uint4 pw4 = recA1[(size_t)j * 2];
        float4 p = *(const float4*)&pw4;
        uint4 mw = recA1[(size_t)j * 2 + 1];
        r = mw.x;
        unsigned r05 = mw.y;
        unsigned meta = mw.z;
        s = meta & 0x7FFFFFu;
        c = meta >> 23;                        // min(cnt,257)
        bound = (c > 256u) || ((s >> 8) != ((s + c - 1) >> 8));

#pragma unroll
        for (int o = 0; o < 32; ++o) at[o] = sW[O_ATB + o];

        // mx1 row (bf16) -> cols 48..63, jj-outer (2 elems per packed word)
        {
            const uint4* m4 = (const uint4*)(mx1 + (size_t)r * 16);
            uint4 a = m4[0], b2 = m4[1];
            unsigned pw[8] = {a.x, a.y, a.z, a.w, b2.x, b2.y, b2.z, b2.w};
#pragma unroll
            for (int k = 0; k < 8; ++k) {
                float e0 = bf2f(pw[k] & 0xFFFFu);
                float e1 = bf2f(pw[k] >> 16);
#pragma unroll
                for (int o = 0; o < 32; ++o)
                    at[o] += e0 * sW[O_ATW + o * 64 + 48 + 2 * k] + e1 * sW[O_ATW + o * 64 + 49 + 2 * k];
            }
        }
        // mx05 row (bf16) -> cols 16..31
        {
            const uint4* m4 = (const uint4*)(mx05 + (size_t)r05 * 16);
            uint4 a = m4[0], b2 = m4[1];
            unsigned pw[8] = {a.x, a.y, a.z, a.w, b2.x, b2.y, b2.z, b2.w};
#pragma unroll
            for (int k = 0; k < 8; ++k) {
                float e0 = bf2f(pw[k] & 0xFFFFu);
                float e1 = bf2f(pw[k] >> 16);
#pragma unroll
                for (int o = 0; o < 32; ++o)
                    at[o] += e0 * sW[O_ATW + o * 64 + 16 + 2 * k] + e1 * sW[O_ATW + o * 64 + 17 + 2 * k];
            }
        }
        // x05 -> cols 0..15: fused compute+consume, x never materialized
        {
            float4 mv = mean05[r05];
            Coords cc = quantc(p.x, p.y, p.z, 512.f, 512.f, 64.f);
            float gx = p.x - (((float)cc.xi + 0.5f) * 0.1f + 0.0f);
            float gy = p.y - (((float)cc.yi + 0.5f) * 0.1f + (-25.6f));
            float gz = p.z - (((float)cc.zi + 0.5f) * 0.1f + (-2.0f));
            float mmx = p.x - mv.x, mmy = p.y - mv.y, mmz = p.z - mv.z;
            float feat[10] = {p.x, p.y, p.z, p.w, mmx, mmy, mmz, gx, gy, gz};
#pragma unroll
            for (int jj = 0; jj < 16; ++jj) {
                float a_ = sW[O_B05 + jj];
#pragma unroll
                for (int q = 0; q < 10; ++q) a_ += feat[q] * sW[O_W05 + jj * 10 + q];
                float g_ = sW[O_WB05 + jj];
#pragma unroll
                for (int q = 0; q < 6; ++q) g_ += feat[4 + q] * sW[O_WW05 + jj * 6 + q];
                float x_ = a_ * g_;
#pragma unroll
                for (int o = 0; o < 32; ++o) at[o] += x_ * sW[O_ATW + o * 64 + jj];
            }
        }
        float mean6[6];
        // x1 -> cols 32..47 (keeps mean6 for am)
        {
            float4 mv = mean1[r];
            Coords cc = quantc(p.x, p.y, p.z, 256.f, 256.f, 32.f);
            float gx = p.x - (((float)cc.xi + 0.5f) * 0.2f + 0.0f);
            float gy = p.y - (((float)cc.yi + 0.5f) * 0.2f + (-25.6f));
            float gz = p.z - (((float)cc.zi + 0.5f) * 0.2f + (-2.0f));
            float mmx = p.x - mv.x, mmy = p.y - mv.y, mmz = p.z - mv.z;
            float feat[10] = {p.x, p.y, p.z, p.w, mmx, mmy, mmz, gx, gy, gz};
            mean6[0] = mmx; mean6[1] = mmy; mean6[2] = mmz;
            mean6[3] = gx;  mean6[4] = gy;  mean6[5] = gz;
#pragma unroll
            for (int jj = 0; jj < 16; ++jj) {
                float a_ = sW[O_B1 + jj];
#pragma unroll
                for (int q = 0; q < 10; ++q) a_ += feat[q] * sW[O_W1 + jj * 10 + q];
                float g_ = sW[O_WB1 + jj];
#pragma unroll
                for (int q = 0; q < 6; ++q) g_ += feat[4 + q] * sW[O_WW1 + jj * 6 + q];
                float x_ = a_ * g_;
#pragma unroll
                for (int o = 0; o < 32; ++o) at[o] += x_ * sW[O_ATW + o * 64 + 32 + jj];
            }
        }
        // h = relu(am)*relu(at), in place (am is a scalar temp per o)
#pragma unroll
        for (int o = 0; o < 32; ++o) {
            float am = sW[O_AMB + o];
#pragma unroll
            for (int q = 0; q < 6; ++q) am += mean6[q] * sW[O_AMW + o * 6 + q];
            at[o] = fmaxf(am, 0.f) * fmaxf(at[o], 0.f);
        }
    } else {
#pragma unroll
        for (int o = 0; o < 32; ++o) at[o] = 0.f;
    }

    bool owner = live && !bound && (j == (int)s);
    unsigned end = s + c;   // interior segments: c exact (<=256), inside block
    unsigned* arow = (unsigned*)outMax + (size_t)r * 32;
    float4* ov = (float4*)(outMax + (size_t)r * 32);

    // ---- phase LO: cols 0..15 streamed to LDS (or atomicMax for boundary) ----
    if (live) {
#pragma unroll
        for (int o = 0; o < 16; ++o) {
            float v = sW[O_AFB + o];
#pragma unroll
            for (int q = 0; q < 32; ++q) v += at[q] * sW[O_AFW + o * 32 + q];
            if (bound) atomicMax(&arow[o], f2o(v));
            else buf[t][o] = v;
        }
    }
    __syncthreads();
    if (owner) {
        float vm[16];
#pragma unroll
        for (int o = 0; o < 16; ++o) vm[o] = buf[t][o];
        for (unsigned j2 = (unsigned)j + 1; j2 < end; ++j2) {
            int t2 = t + (int)(j2 - (unsigned)j);
#pragma unroll
            for (int o = 0; o < 16; ++o) vm[o] = fmaxf(vm[o], buf[t2][o]);
        }
#pragma unroll
        for (int k = 0; k < 4; ++k)
            ov[k] = make_float4(vm[4 * k], vm[4 * k + 1], vm[4 * k + 2], vm[4 * k + 3]);
    }
    __syncthreads();
    // ---- phase HI: cols 16..31 ----
    if (live) {
#pragma unroll
        for (int o = 0; o < 16; ++o) {
            float v = sW[O_AFB + 16 + o];
#pragma unroll
            for (int q = 0; q < 32; ++q) v += at[q] * sW[O_AFW + (16 + o) * 32 + q];
            if (bound) atomicMax(&arow[16 + o], f2o(v));
            else buf[t][o] = v;
        }
    }
    __syncthreads();
    if (owner) {
        float vm[16];
#pragma unroll
        for (int o = 0; o < 16; ++o) vm[o] = buf[t][o];
        for (unsigned j2 = (unsigned)j + 1; j2 < end; ++j2) {
            int t2 = t + (int)(j2 - (unsigned)j);
#pragma unroll
            for (int o = 0; o < 16; ++o) vm[o] = fmaxf(vm[o], buf[t2][o]);
        }
#pragma unroll
        for (int k = 0; k < 4; ++k)
            ov[4 + k] = make_float4(vm[4 * k], vm[4 * k + 1], vm[4 * k + 2], vm[4 * k + 3]);
    }
}

// row-per-thread finalize: untransform boundary rows; zero pad rows (maxf + coords)
__global__ __launch_bounds__(256) void k_finrow(
    float* __restrict__ outMax, float* __restrict__ outCoord,
    const unsigned char* __restrict__ flags, const unsigned* __restrict__ U1p, int n) {
    int r = blockIdx.x * 256 + threadIdx.x;
    if (r >= n) return;
    unsigned U = *U1p;
    if ((unsigned)r >= U) {
        float4 z = make_float4(0.f, 0.f, 0.f, 0.f);
        float4* row = (float4*)(outMax + (size_t)r * 32);
#pragma unroll
        for (int k = 0; k < 8; ++k) row[k] = z;
        ((float4*)outCoord)[r] = z;
    } else if (flags[r]) {
        unsigned* urow = (unsigned*)outMax + (size_t)r * 32;
        float* frow = outMax + (size_t)r * 32;
#pragma unroll
        for (int o = 0; o < 32; ++o) frow[o] = o2f(urow[o]);
    }
}

// ---------------- host launch ----------------

extern "C" void kernel_launch(void* const* d_in, const int* in_sizes, int n_in,
                              void* d_out, int out_size, void* d_ws, size_t ws_size,
                              hipStream_t stream) {
    const float4* pc = (const float4*)d_in[0];
    const int* ind   = (const int*)d_in[1];
    const float* w05 = (const float*)d_in[2];
    const float* b05 = (const float*)d_in[3];
    const float* ww05 = (const float*)d_in[4];
    const float* wb05 = (const float*)d_in[5];
    const float* w1  = (const float*)d_in[6];
    const float* b1  = (const float*)d_in[7];
    const float* ww1 = (const float*)d_in[8];
    const float* wb1 = (const float*)d_in[9];
    const float* am_w = (const float*)d_in[10];
    const float* am_b = (const float*)d_in[11];
    const float* at_w = (const float*)d_in[12];
    const float* at_b = (const float*)d_in[13];
    const float* af_w = (const float*)d_in[14];
    const float* af_b = (const float*)d_in[15];

    int n = in_sizes[0] / 4;
    int B = in_sizes[1] - 1;

    int nW05 = B * (512 * 512 * 64 / 32);
    int nW1  = B * (256 * 256 * 32 / 32);
    int nB05 = (nW05 + 2047) / 2048;
    int nB1  = (nW1 + 2047) / 2048;
    int nCh  = (n + 2047) / 2048;

    size_t off = 0;
    char* base = (char*)d_ws;
    auto take = [&](size_t bytes) -> char* {
        char* p = base + off;
        off = (off + bytes + 255) & ~(size_t)255;
        return p;
    };

    // zero-init group (single contiguous memset)
    unsigned* mask05 = (unsigned*)take((size_t)nW05 * 4);
    unsigned* mask1  = (unsigned*)take((size_t)nW1 * 4);
    unsigned* cnt05  = (unsigned*)take((size_t)n * 4);
    unsigned* cnt1   = (unsigned*)take((size_t)n * 4);
    unsigned char* flags = (unsigned char*)take((size_t)n);
    size_t zeroBytes = off;

    unsigned* wp05   = (unsigned*)take((size_t)nW05 * 4);
    unsigned* wp1    = (unsigned*)take((size_t)nW1 * 4);
    unsigned* inv05  = (unsigned*)take((size_t)n * 4);
    unsigned* inv1   = (unsigned*)take((size_t)n * 4);
    unsigned* slot05 = (unsigned*)take((size_t)n * 4);
    unsigned* slot1  = (unsigned*)take((size_t)n * 4);
    unsigned* start05 = (unsigned*)take((size_t)n * 4);
    unsigned* start1  = (unsigned*)take((size_t)n * 4);
    uint4*    recA05  = (uint4*)take((size_t)n * 32);  // {p | r05,-,-,-}
    uint4*    recA1   = (uint4*)take((size_t)n * 32);  // {p | r1,r05,meta,-}
    float4*   mean05  = (float4*)take((size_t)n * 16);
    float4*   mean1   = (float4*)take((size_t)n * 16);
    unsigned short* mx05 = (unsigned short*)take((size_t)n * 32);  // bf16 [n][16]
    unsigned short* mx1  = (unsigned short*)take((size_t)n * 32);
    unsigned* bsum05  = (unsigned*)take((size_t)nB05 * 4);
    unsigned* bpref05 = (unsigned*)take((size_t)nB05 * 4);
    unsigned* bsum1   = (unsigned*)take((size_t)nB1 * 4);
    unsigned* bpref1  = (unsigned*)take((size_t)nB1 * 4);
    unsigned* bsC05   = (unsigned*)take((size_t)nCh * 4);
    unsigned* bpC05   = (unsigned*)take((size_t)nCh * 4);
    unsigned* bsC1    = (unsigned*)take((size_t)nCh * 4);
    unsigned* bpC1    = (unsigned*)take((size_t)nCh * 4);
    unsigned* U1p     = (unsigned*)take(4);
    size_t total = off;

    if (ws_size < total) {
        fprintf(stderr, "kernel_launch: ws too small (%zu < %zu)\n", ws_size, total);
        return;
    }

    float* outMaxF = (float*)d_out;                      // [n,32]
    float* outCoord = (float*)d_out + (size_t)n * 32;    // [n,4]
    float* outInv = (float*)d_out + (size_t)n * 36;      // [n]

    hipMemsetAsync(d_ws, 0, zeroBytes, stream);

    int gpts = (n + 255) / 256;
    int nbb  = (gpts + 255) / 256;
    // unique-rank machinery (both scales per launch)
    k_bits<<<gpts, 256, 0, stream>>>(pc, ind, B, n, mask05, mask1);
    k_chunk2<<<nB05 + nB1, 256, 0, stream>>>(mask05, bsum05, nW05, nB05,
                                             mask1, bsum1, nW1);
    k_scan2<<<2, 1024, 0, stream>>>(bsum05, bpref05, nullptr, nB05,
                                    bsum1, bpref1, U1p, nB1);
    k_wpref2<<<nB05 + nB1, 256, 0, stream>>>(mask05, bpref05, wp05, nW05, nB05,
                                             mask1, bpref1, wp1, nW1);
    // ranks + counts + slots (one atomic per point per scale)
    k_rank<<<gpts, 256, 0, stream>>>(pc, ind, B, n, mask05, wp05, mask1, wp1,
                                     inv05, inv1, cnt05, cnt1, slot05, slot1,
                                     outCoord, outInv);
    // CSR starts
    k_chunku2<<<2 * nCh, 256, 0, stream>>>(cnt05, bsC05, cnt1, bsC1, n, nCh);
    k_scan2<<<2, 1024, 0, stream>>>(bsC05, bpC05, nullptr, nCh,
                                    bsC1, bpC1, nullptr, nCh);
    k_eprefu2<<<2 * nCh, 256, 0, stream>>>(cnt05, bpC05, start05,
                                           cnt1, bpC1, start1, n, nCh);
    // counting-sort scatter of 32B point records (plain stores)
    k_slot<<<gpts, 256, 0, stream>>>(pc, inv05, inv1, slot05, slot1,
                                     start05, start1, cnt1, recA05, recA1, n);
    // per-voxel means (both scales) + boundary flags/binit (third range)
    k_segmean2<<<2 * gpts + nbb, 256, 0, stream>>>(recA05, start05, cnt05, mean05,
                                                   recA1, start1, cnt1, mean1,
                                                   flags, (unsigned*)outMaxF, n, gpts);
    // per-voxel mx (bf16), both scales in one launch
    k_segmx2<<<2 * gpts, 256, 0, stream>>>(recA05, start05, cnt05, mean05,
                                           w05, b05, ww05, wb05, mx05,
                                           recA1, start1, cnt1, mean1,
                                           w1, b1, ww1, wb1, mx1, n, gpts);
    // fused pipeline + two-phase segmented max (weights in LDS)
    k_val<<<gpts, 256, 0, stream>>>(recA1,
                                    mean05, mx05, mean1, mx1,
                                    w05, b05, ww05, wb05, w1, b1, ww1, wb1,
                                    am_w, am_b, at_w, at_b, af_w, af_b,
                                    outMaxF, n);
    // untransform boundary rows + zero pad rows (row-per-thread)
    k_finrow<<<gpts, 256, 0, stream>>>(outMaxF, outCoord, flags, U1p, n);

    (void)n_in; (void)out_size;
}

// Round 9
// 735.705 us; speedup vs baseline: 2.1353x; 2.1353x over previous
//
#include <hip/hip_runtime.h>
#include <cstdint>
#include <cstdio>

// ---------------- device helpers ----------------

struct Coords { int xi, yi, zi; };

// EXACT replication of reference quantization (all f32 ops, truncating cast)
__device__ __forceinline__ Coords quantc(float x, float y, float z, float sx, float sy, float sz) {
    Coords c;
    c.xi = (int)(((x - 0.0f)  / 51.2f) * sx);
    c.yi = (int)(((y + 25.6f) / 51.2f) * sy);
    c.zi = (int)(((z + 2.0f)  / 6.4f)  * sz);
    return c;
}

__device__ __forceinline__ int batch_of(int i, const int* __restrict__ ind, int B) {
    int bt = 0;
    for (int b = 1; b < B; ++b) if (i >= ind[b]) bt = b;
    return bt;
}

// order-preserving float<->uint transform for atomicMax on signed floats
__device__ __forceinline__ unsigned f2o(float f) {
    unsigned u = __float_as_uint(f);
    return (u & 0x80000000u) ? ~u : (u | 0x80000000u);
}
__device__ __forceinline__ float o2f(unsigned u) {
    return (u & 0x80000000u) ? __uint_as_float(u ^ 0x80000000u) : __uint_as_float(~u);
}
#define NEG_O 0x007FFFFFu   // f2o(-inf)

// bf16 helpers (RTNE)
__device__ __forceinline__ unsigned short f2bf(float x) {
    unsigned u = __float_as_uint(x);
    unsigned r = (u + 0x7FFFu + ((u >> 16) & 1u)) >> 16;
    return (unsigned short)r;
}
__device__ __forceinline__ float bf2f(unsigned h) {
    return __uint_as_float(h << 16);
}

// x[16] = (feat@W.T + b) * (mean@Ww.T + wb);  mean6 out = [mm, gmm]
__device__ __forceinline__ void compute_x16(
    float px, float py, float pz, float pw,
    float mx_, float my_, float mz_, Coords c,
    const float* __restrict__ W, const float* __restrict__ Bv,
    const float* __restrict__ Ww, const float* __restrict__ Wb,
    float* __restrict__ x, float* __restrict__ mean6) {
    float gx = px - (((float)c.xi + 0.5f) * 0.2f + 0.0f);
    float gy = py - (((float)c.yi + 0.5f) * 0.2f + (-25.6f));
    float gz = pz - (((float)c.zi + 0.5f) * 0.2f + (-2.0f));
    float mmx = px - mx_, mmy = py - my_, mmz = pz - mz_;
    float feat[10] = {px, py, pz, pw, mmx, mmy, mmz, gx, gy, gz};
    float mean[6]  = {mmx, mmy, mmz, gx, gy, gz};
#pragma unroll
    for (int j = 0; j < 6; ++j) mean6[j] = mean[j];
#pragma unroll
    for (int o = 0; o < 16; ++o) {
        float a = Bv[o];
#pragma unroll
        for (int j = 0; j < 10; ++j) a += feat[j] * W[o * 10 + j];
        float g = Wb[o];
#pragma unroll
        for (int j = 0; j < 6; ++j) g += mean[j] * Ww[o * 6 + j];
        x[o] = a * g;
    }
}

// ---------------- bitmask unique-rank machinery ----------------

__global__ __launch_bounds__(256) void k_bits(
    const float4* __restrict__ pc, const int* __restrict__ ind, int B, int n,
    unsigned* __restrict__ mask05, unsigned* __restrict__ mask1) {
    int i = blockIdx.x * 256 + threadIdx.x;
    if (i >= n) return;
    float4 p = pc[i];
    int bt = batch_of(i, ind, B);
    Coords c05 = quantc(p.x, p.y, p.z, 512.f, 512.f, 64.f);
    Coords c1  = quantc(p.x, p.y, p.z, 256.f, 256.f, 32.f);
    int lid05 = ((bt * 512 + c05.xi) * 512 + c05.yi) * 64 + c05.zi;
    int lid1  = ((bt * 256 + c1.xi)  * 256 + c1.yi)  * 32 + c1.zi;
    atomicOr(&mask05[lid05 >> 5], 1u << (lid05 & 31));
    atomicOr(&mask1[lid1 >> 5],  1u << (lid1 & 31));
}

// transpose at_w [32][64] -> atT [64][32] so k_val's o-inner loop reads 32
// CONSECUTIVE dwords per column (scalar-load batching; round-8 lesson:
// uniform weights live in SGPRs via s_load — make them batchable, never
// stage them in LDS).
__global__ __launch_bounds__(256) void k_wtr(
    const float* __restrict__ at_w, float* __restrict__ atT) {
    int i = blockIdx.x * 256 + threadIdx.x;
    if (i >= 2048) return;
    int o = i >> 6, c = i & 63;
    atT[c * 32 + o] = at_w[i];
}

// merged popc-chunk over BOTH masks (blockIdx split)
__global__ __launch_bounds__(256) void k_chunk2(
    const unsigned* __restrict__ maskA, unsigned* __restrict__ bsumA, int nWA, int nBA,
    const unsigned* __restrict__ maskB, unsigned* __restrict__ bsumB, int nWB) {
    const unsigned* mask; unsigned* bsum; int nW, blk;
    if ((int)blockIdx.x < nBA) { mask = maskA; bsum = bsumA; nW = nWA; blk = blockIdx.x; }
    else { mask = maskB; bsum = bsumB; nW = nWB; blk = blockIdx.x - nBA; }
    int t = threadIdx.x;
    int base = blk * 2048 + t;
    unsigned tot = 0;
#pragma unroll
    for (int k = 0; k < 8; ++k) {
        int w = base + k * 256;
        if (w < nW) tot += __popc(mask[w]);
    }
    __shared__ unsigned s[256];
    s[t] = tot;
    __syncthreads();
    for (int off = 128; off > 0; off >>= 1) {
        if (t < off) s[t] += s[t + off];
        __syncthreads();
    }
    if (t == 0) bsum[blk] = s[0];
}

// merged chunk-sum over both cnt arrays
__global__ __launch_bounds__(256) void k_chunku2(
    const unsigned* __restrict__ cntA, unsigned* __restrict__ bsumA,
    const unsigned* __restrict__ cntB, unsigned* __restrict__ bsumB,
    int nElem, int nCh) {
    const unsigned* val; unsigned* bsum; int blk;
    if ((int)blockIdx.x < nCh) { val = cntA; bsum = bsumA; blk = blockIdx.x; }
    else { val = cntB; bsum = bsumB; blk = blockIdx.x - nCh; }
    int t = threadIdx.x;
    int base = blk * 2048 + t;
    unsigned tot = 0;
#pragma unroll
    for (int k = 0; k < 8; ++k) {
        int w = base + k * 256;
        if (w < nElem) tot += val[w];
    }
    __shared__ unsigned s[256];
    s[t] = tot;
    __syncthreads();
    for (int off = 128; off > 0; off >>= 1) {
        if (t < off) s[t] += s[t + off];
        __syncthreads();
    }
    if (t == 0) bsum[blk] = s[0];
}

// merged single-block scans: block 0 does set A, block 1 set B
__global__ __launch_bounds__(1024) void k_scan2(
    const unsigned* __restrict__ bsumA, unsigned* __restrict__ bprefA,
    unsigned* __restrict__ UoutA, int nA,
    const unsigned* __restrict__ bsumB, unsigned* __restrict__ bprefB,
    unsigned* __restrict__ UoutB, int nB) {
    const unsigned* bsum; unsigned* bpref; unsigned* Uout; int nBn;
    if (blockIdx.x == 0) { bsum = bsumA; bpref = bprefA; Uout = UoutA; nBn = nA; }
    else { bsum = bsumB; bpref = bprefB; Uout = UoutB; nBn = nB; }
    __shared__ unsigned s[1024];
    int t = threadIdx.x;
    int ipt = (nBn + 1023) >> 10;
    unsigned tot = 0;
    for (int k = 0; k < ipt; ++k) {
        int e = t * ipt + k;
        if (e < nBn) tot += bsum[e];
    }
    s[t] = tot;
    __syncthreads();
    for (int off = 1; off < 1024; off <<= 1) {
        unsigned v = 0;
        if (t >= off) v = s[t - off];
        __syncthreads();
        if (t >= off) s[t] += v;
        __syncthreads();
    }
    unsigned run = s[t] - tot;  // exclusive
    for (int k = 0; k < ipt; ++k) {
        int e = t * ipt + k;
        if (e < nBn) { bpref[e] = run; run += bsum[e]; }
    }
    if (t == 1023 && Uout) *Uout = s[1023];
}

// merged per-word prefix over both masks
__global__ __launch_bounds__(256) void k_wpref2(
    const unsigned* __restrict__ maskA, const unsigned* __restrict__ bprefA,
    unsigned* __restrict__ wprefA, int nWA, int nBA,
    const unsigned* __restrict__ maskB, const unsigned* __restrict__ bprefB,
    unsigned* __restrict__ wprefB, int nWB) {
    const unsigned* mask; const unsigned* bpref; unsigned* wpref; int nW, blk;
    if ((int)blockIdx.x < nBA) { mask = maskA; bpref = bprefA; wpref = wprefA; nW = nWA; blk = blockIdx.x; }
    else { mask = maskB; bpref = bprefB; wpref = wprefB; nW = nWB; blk = blockIdx.x - nBA; }
    int t = threadIdx.x;
    int base = blk * 2048 + t * 8;
    unsigned p[8];
    unsigned tot = 0;
#pragma unroll
    for (int k = 0; k < 8; ++k) {
        int w = base + k;
        p[k] = (w < nW) ? __popc(mask[w]) : 0u;
        tot += p[k];
    }
    __shared__ unsigned s[256];
    s[t] = tot;
    __syncthreads();
    for (int off = 1; off < 256; off <<= 1) {
        unsigned v = 0;
        if (t >= off) v = s[t - off];
        __syncthreads();
        if (t >= off) s[t] += v;
        __syncthreads();
    }
    unsigned run = bpref[blk] + (s[t] - tot);
#pragma unroll
    for (int k = 0; k < 8; ++k) {
        int w = base + k;
        if (w < nW) { wpref[w] = run; run += p[k]; }
    }
}

// merged element prefix over both cnt arrays -> start offsets
__global__ __launch_bounds__(256) void k_eprefu2(
    const unsigned* __restrict__ cntA, const unsigned* __restrict__ bprefA,
    unsigned* __restrict__ startA,
    const unsigned* __restrict__ cntB, const unsigned* __restrict__ bprefB,
    unsigned* __restrict__ startB,
    int nElem, int nCh) {
    const unsigned* val; const unsigned* bpref; unsigned* epref; int blk;
    if ((int)blockIdx.x < nCh) { val = cntA; bpref = bprefA; epref = startA; blk = blockIdx.x; }
    else { val = cntB; bpref = bprefB; epref = startB; blk = blockIdx.x - nCh; }
    int t = threadIdx.x;
    int base = blk * 2048 + t * 8;
    unsigned p[8];
    unsigned tot = 0;
#pragma unroll
    for (int k = 0; k < 8; ++k) {
        int w = base + k;
        p[k] = (w < nElem) ? val[w] : 0u;
        tot += p[k];
    }
    __shared__ unsigned s[256];
    s[t] = tot;
    __syncthreads();
    for (int off = 1; off < 256; off <<= 1) {
        unsigned v = 0;
        if (t >= off) v = s[t - off];
        __syncthreads();
        if (t >= off) s[t] += v;
        __syncthreads();
    }
    unsigned run = bpref[blk] + (s[t] - tot);
#pragma unroll
    for (int k = 0; k < 8; ++k) {
        int w = base + k;
        if (w < nElem) { epref[w] = run; run += p[k]; }
    }
}

// ---------------- point passes ----------------

// ranks + counts + slots. ONE scattered atomic per point per scale — the
// atomicAdd's return value IS the slot. outCoord written once per voxel.
__global__ __launch_bounds__(256) void k_rank(
    const float4* __restrict__ pc, const int* __restrict__ ind, int B, int n,
    const unsigned* __restrict__ mask05, const unsigned* __restrict__ wp05,
    const unsigned* __restrict__ mask1, const unsigned* __restrict__ wp1,
    unsigned* __restrict__ inv05, unsigned* __restrict__ inv1,
    unsigned* __restrict__ cnt05, unsigned* __restrict__ cnt1,
    unsigned* __restrict__ slot05, unsigned* __restrict__ slot1,
    float* __restrict__ outCoord, float* __restrict__ outInv) {
    int i = blockIdx.x * 256 + threadIdx.x;
    if (i >= n) return;
    float4 p = pc[i];
    int bt = batch_of(i, ind, B);
    Coords c05 = quantc(p.x, p.y, p.z, 512.f, 512.f, 64.f);
    Coords c1  = quantc(p.x, p.y, p.z, 256.f, 256.f, 32.f);
    int lid05 = ((bt * 512 + c05.xi) * 512 + c05.yi) * 64 + c05.zi;
    int lid1  = ((bt * 256 + c1.xi)  * 256 + c1.yi)  * 32 + c1.zi;

    unsigned w = (unsigned)lid05 >> 5, b = (unsigned)lid05 & 31u;
    unsigned r05 = wp05[w] + __popc(mask05[w] & ((1u << b) - 1u));
    w = (unsigned)lid1 >> 5; b = (unsigned)lid1 & 31u;
    unsigned r1 = wp1[w] + __popc(mask1[w] & ((1u << b) - 1u));

    inv05[i] = r05;
    inv1[i] = r1;
    outInv[i] = (float)r1;

    slot05[i] = atomicAdd(&cnt05[r05], 1u);
    unsigned sl1 = atomicAdd(&cnt1[r1], 1u);
    slot1[i] = sl1;
    if (sl1 == 0u)
        ((float4*)outCoord)[r1] = make_float4((float)bt, (float)c1.xi, (float)c1.yi, (float)c1.zi);
}

// counting-sort scatter of 32B point records into CSR order.
// recA05[2j]={p}, recA05[2j+1]={r05,-,-,-}
// recA1 [2j]={p}, recA1 [2j+1]={r1, r05, meta,-}; meta = start1 | min(cnt1,257)<<23
__global__ __launch_bounds__(256) void k_slot(
    const float4* __restrict__ pc,
    const unsigned* __restrict__ inv05, const unsigned* __restrict__ inv1,
    const unsigned* __restrict__ slot05, const unsigned* __restrict__ slot1,
    const unsigned* __restrict__ start05, const unsigned* __restrict__ start1,
    const unsigned* __restrict__ cnt1,
    uint4* __restrict__ recA05, uint4* __restrict__ recA1, int n) {
    int i = blockIdx.x * 256 + threadIdx.x;
    if (i >= n) return;
    float4 p = pc[i];
    unsigned r05 = inv05[i], r1 = inv1[i];
    unsigned p05 = start05[r05] + slot05[i];
    unsigned s1 = start1[r1];
    unsigned p1  = s1 + slot1[i];
    unsigned c1 = cnt1[r1];
    unsigned cm = c1 < 257u ? c1 : 257u;
    unsigned meta = s1 | (cm << 23);
    uint4 pw = *(const uint4*)&p;
    recA05[(size_t)p05 * 2]     = pw;
    recA05[(size_t)p05 * 2 + 1] = make_uint4(r05, 0u, 0u, 0u);
    recA1[(size_t)p1 * 2]       = pw;
    recA1[(size_t)p1 * 2 + 1]   = make_uint4(r1, r05, meta, 0u);
}

// merged: wave-level segmented mean over CSR records for BOTH scales, plus the
// boundary-flag/binit pass as a third blockIdx range. Points read coalesced.
__global__ __launch_bounds__(256) void k_segmean2(
    const uint4* __restrict__ recA05, const unsigned* __restrict__ start05,
    const unsigned* __restrict__ cnt05, float4* __restrict__ mean05,
    const uint4* __restrict__ recA1, const unsigned* __restrict__ start1,
    const unsigned* __restrict__ cnt1, float4* __restrict__ mean1,
    unsigned char* __restrict__ flags, unsigned* __restrict__ outMaxU,
    int n, int gpts) {
    // third range: boundary-segment flags + atomicMax row init
    if ((int)blockIdx.x >= 2 * gpts) {
        int blk3 = blockIdx.x - 2 * gpts;
        int b = blk3 * 256 + threadIdx.x + 1;
        if (b >= gpts) return;
        int j = b * 256;
        if (j >= n) return;
        unsigned r = recA1[(size_t)j * 2 + 1].x;
        if (start1[r] < (unsigned)j) {
            flags[r] = 1;
            unsigned* row = outMaxU + (size_t)r * 32;
#pragma unroll
            for (int o = 0; o < 32; ++o) row[o] = NEG_O;
        }
        return;
    }
    const uint4* recA; const unsigned* start; const unsigned* cnt;
    float4* meanOut; int blk;
    if ((int)blockIdx.x < gpts) {
        recA = recA05; start = start05; cnt = cnt05; meanOut = mean05; blk = blockIdx.x;
    } else {
        recA = recA1; start = start1; cnt = cnt1; meanOut = mean1; blk = blockIdx.x - gpts;
    }
    int j = blk * 256 + threadIdx.x;
    int lane = threadIdx.x & 63;
    bool live = j < n;
    unsigned r = 0xFFFFFFFFu;
    float sx = 0.f, sy = 0.f, sz = 0.f;
    if (live) {
        float4 p = *(const float4*)&recA[(size_t)j * 2];
        r = recA[(size_t)j * 2 + 1].x;
        sx = p.x; sy = p.y; sz = p.z;
    }
#pragma unroll
    for (int d = 1; d < 64; d <<= 1) {
        unsigned rn = (unsigned)__shfl_down((int)r, d);
        float ax = __shfl_down(sx, d);
        float ay = __shfl_down(sy, d);
        float az = __shfl_down(sz, d);
        bool ok = (lane + d) < 64 && rn == r;
        if (ok) { sx += ax; sy += ay; sz += az; }
    }
    if (!live) return;
    if (j != (int)start[r]) return;
    unsigned c = cnt[r];
    unsigned end = j + c;
    unsigned waveEnd = ((unsigned)j & ~63u) + 64u;
    for (unsigned j2 = waveEnd; j2 < end; ++j2) {
        float4 q = *(const float4*)&recA[(size_t)j2 * 2];
        sx += q.x; sy += q.y; sz += q.z;
    }
    float cf = (float)c;
    meanOut[r] = make_float4(sx / cf, sy / cf, sz / cf, 0.f);
}

// merged block-level LDS segmented max of x16 for BOTH scales (blockIdx split)
__global__ __launch_bounds__(256) void k_segmx2(
    const uint4* __restrict__ recA05, const unsigned* __restrict__ start05,
    const unsigned* __restrict__ cnt05, const float4* __restrict__ mean05,
    const float* __restrict__ w05, const float* __restrict__ b05,
    const float* __restrict__ ww05, const float* __restrict__ wb05,
    unsigned short* __restrict__ mx05,
    const uint4* __restrict__ recA1, const unsigned* __restrict__ start1,
    const unsigned* __restrict__ cnt1, const float4* __restrict__ mean1,
    const float* __restrict__ w1, const float* __restrict__ b1,
    const float* __restrict__ ww1, const float* __restrict__ wb1,
    unsigned short* __restrict__ mx1,
    int n, int gpts) {
    const uint4* recA; const unsigned* start; const unsigned* cnt;
    const float4* meanIn; const float* W; const float* Bv; const float* Ww;
    const float* Wb; unsigned short* mxOut; int blk;
    float sx_, sy_, sz_;
    if ((int)blockIdx.x < gpts) {
        recA = recA05; start = start05; cnt = cnt05; meanIn = mean05;
        W = w05; Bv = b05; Ww = ww05; Wb = wb05; mxOut = mx05;
        sx_ = 512.f; sy_ = 512.f; sz_ = 64.f; blk = blockIdx.x;
    } else {
        recA = recA1; start = start1; cnt = cnt1; meanIn = mean1;
        W = w1; Bv = b1; Ww = ww1; Wb = wb1; mxOut = mx1;
        sx_ = 256.f; sy_ = 256.f; sz_ = 32.f; blk = blockIdx.x - gpts;
    }
    __shared__ float buf[256][17];
    int t = threadIdx.x;
    int j = blk * 256 + t;
    bool live = j < n;
    unsigned r = 0;
    float x[16], d6[6];
    if (live) {
        float4 p = *(const float4*)&recA[(size_t)j * 2];
        r = recA[(size_t)j * 2 + 1].x;
        float4 mv = meanIn[r];
        Coords cc = quantc(p.x, p.y, p.z, sx_, sy_, sz_);
        compute_x16(p.x, p.y, p.z, p.w, mv.x, mv.y, mv.z, cc, W, Bv, Ww, Wb, x, d6);
    } else {
#pragma unroll
        for (int o = 0; o < 16; ++o) x[o] = 0.f;
    }
#pragma unroll
    for (int o = 0; o < 16; ++o) buf[t][o] = x[o];
    __syncthreads();
    if (!live || j != (int)start[r]) return;
    unsigned c = cnt[r];
    unsigned end = j + c;
    unsigned blockEnd = ((unsigned)blk + 1u) * 256u;
    unsigned inEnd = end < blockEnd ? end : blockEnd;
    for (unsigned j2 = j + 1; j2 < inEnd; ++j2) {
        int t2 = t + (int)(j2 - (unsigned)j);
#pragma unroll
        for (int o = 0; o < 16; ++o) x[o] = fmaxf(x[o], buf[t2][o]);
    }
    float4 mv = meanIn[r];
    for (unsigned j2 = blockEnd; j2 < end; ++j2) {
        float4 q = *(const float4*)&recA[(size_t)j2 * 2];
        Coords cc = quantc(q.x, q.y, q.z, sx_, sy_, sz_);
        float x2[16];
        compute_x16(q.x, q.y, q.z, q.w, mv.x, mv.y, mv.z, cc, W, Bv, Ww, Wb, x2, d6);
#pragma unroll
        for (int o = 0; o < 16; ++o) x[o] = fmaxf(x[o], x2[o]);
    }
    unsigned pk[8];
#pragma unroll
    for (int k = 0; k < 8; ++k)
        pk[k] = (unsigned)f2bf(x[2 * k]) | ((unsigned)f2bf(x[2 * k + 1]) << 16);
    uint4* mr = (uint4*)(mxOut + (size_t)r * 16);
    mr[0] = make_uint4(pk[0], pk[1], pk[2], pk[3]);
    mr[1] = make_uint4(pk[4], pk[5], pk[6], pk[7]);
}

// fused per-point pipeline + two-phase in-block segmented max.
// Weights read directly from global (uniform -> scalar loads; round-8 lesson:
// LDS-staging them spills VGPRs). at_w accessed via atT (transposed) so the
// o-inner loop reads 32 consecutive dwords -> batched s_load instead of 1536
// isolated strided scalar loads.
// (256,3): round-4 lesson — tighter caps spill at[32] to scratch.
__global__ __launch_bounds__(256, 3) void k_val(
    const uint4* __restrict__ recA1,
    const float4* __restrict__ mean05, const unsigned short* __restrict__ mx05,
    const float4* __restrict__ mean1, const unsigned short* __restrict__ mx1,
    const float* __restrict__ w05, const float* __restrict__ b05,
    const float* __restrict__ ww05, const float* __restrict__ wb05,
    const float* __restrict__ w1g, const float* __restrict__ b1g,
    const float* __restrict__ ww1, const float* __restrict__ wb1,
    const float* __restrict__ am_w, const float* __restrict__ am_b,
    const float* __restrict__ atT, const float* __restrict__ at_b,
    const float* __restrict__ af_w, const float* __restrict__ af_b,
    float* __restrict__ outMax, int n) {
    __shared__ float buf[256][17];
    int t = threadIdx.x;
    int j = blockIdx.x * 256 + t;
    bool live = j < n;
    unsigned r = 0, s = 0, c = 0;
    bool bound = false;
    float at[32];
    if (live) {
        uint4 pw4 = recA1[(size_t)j * 2];
        float4 p = *(const float4*)&pw4;
        uint4 mw = recA1[(size_t)j * 2 + 1];
        r = mw.x;
        unsigned r05 = mw.y;
        unsigned meta = mw.z;
        s = meta & 0x7FFFFFu;
        c = meta >> 23;                        // min(cnt,257)
        bound = (c > 256u) || ((s >> 8) != ((s + c - 1) >> 8));

#pragma unroll
        for (int o = 0; o < 32; ++o) at[o] = at_b[o];

        // mx1 row (bf16) -> cols 48..63, jj-outer (2 elems per packed word)
        {
            const uint4* m4 = (const uint4*)(mx1 + (size_t)r * 16);
            uint4 a = m4[0], b2 = m4[1];
            unsigned pw[8] = {a.x, a.y, a.z, a.w, b2.x, b2.y, b2.z, b2.w};
#pragma unroll
            for (int k = 0; k < 8; ++k) {
                float e0 = bf2f(pw[k] & 0xFFFFu);
                float e1 = bf2f(pw[k] >> 16);
#pragma unroll
                for (int o = 0; o < 32; ++o)
                    at[o] += e0 * atT[(48 + 2 * k) * 32 + o] + e1 * atT[(49 + 2 * k) * 32 + o];
            }
        }
        // mx05 row (bf16) -> cols 16..31
        {
            const uint4* m4 = (const uint4*)(mx05 + (size_t)r05 * 16);
            uint4 a = m4[0], b2 = m4[1];
            unsigned pw[8] = {a.x, a.y, a.z, a.w, b2.x, b2.y, b2.z, b2.w};
#pragma unroll
            for (int k = 0; k < 8; ++k) {
                float e0 = bf2f(pw[k] & 0xFFFFu);
                float e1 = bf2f(pw[k] >> 16);
#pragma unroll
                for (int o = 0; o < 32; ++o)
                    at[o] += e0 * atT[(16 + 2 * k) * 32 + o] + e1 * atT[(17 + 2 * k) * 32 + o];
            }
        }
        // x05 -> cols 0..15: fused compute+consume, x never materialized
        {
            float4 mv = mean05[r05];
            Coords cc = quantc(p.x, p.y, p.z, 512.f, 512.f, 64.f);
            float gx = p.x - (((float)cc.xi + 0.5f) * 0.1f + 0.0f);
            float gy = p.y - (((float)cc.yi + 0.5f) * 0.1f + (-25.6f));
            float gz = p.z - (((float)cc.zi + 0.5f) * 0.1f + (-2.0f));
            float mmx = p.x - mv.x, mmy = p.y - mv.y, mmz = p.z - mv.z;
            float feat[10] = {p.x, p.y, p.z, p.w, mmx, mmy, mmz, gx, gy, gz};
#pragma unroll
            for (int jj = 0; jj < 16; ++jj) {
                float a_ = b05[jj];
#pragma unroll
                for (int q = 0; q < 10; ++q) a_ += feat[q] * w05[jj * 10 + q];
                float g_ = wb05[jj];
#pragma unroll
                for (int q = 0; q < 6; ++q) g_ += feat[4 + q] * ww05[jj * 6 + q];
                float x_ = a_ * g_;
#pragma unroll
                for (int o = 0; o < 32; ++o) at[o] += x_ * atT[jj * 32 + o];
            }
        }
        float mean6[6];
        // x1 -> cols 32..47 (keeps mean6 for am)
        {
            float4 mv = mean1[r];
            Coords cc = quantc(p.x, p.y, p.z, 256.f, 256.f, 32.f);
            float gx = p.x - (((float)cc.xi + 0.5f) * 0.2f + 0.0f);
            float gy = p.y - (((float)cc.yi + 0.5f) * 0.2f + (-25.6f));
            float gz = p.z - (((float)cc.zi + 0.5f) * 0.2f + (-2.0f));
            float mmx = p.x - mv.x, mmy = p.y - mv.y, mmz = p.z - mv.z;
            float feat[10] = {p.x, p.y, p.z, p.w, mmx, mmy, mmz, gx, gy, gz};
            mean6[0] = mmx; mean6[1] = mmy; mean6[2] = mmz;
            mean6[3] = gx;  mean6[4] = gy;  mean6[5] = gz;
#pragma unroll
            for (int jj = 0; jj < 16; ++jj) {
                float a_ = b1g[jj];
#pragma unroll
                for (int q = 0; q < 10; ++q) a_ += feat[q] * w1g[jj * 10 + q];
                float g_ = wb1[jj];
#pragma unroll
                for (int q = 0; q < 6; ++q) g_ += feat[4 + q] * ww1[jj * 6 + q];
                float x_ = a_ * g_;
#pragma unroll
                for (int o = 0; o < 32; ++o) at[o] += x_ * atT[(32 + jj) * 32 + o];
            }
        }
        // h = relu(am)*relu(at), in place (am is a scalar temp per o)
#pragma unroll
        for (int o = 0; o < 32; ++o) {
            float am = am_b[o];
#pragma unroll
            for (int q = 0; q < 6; ++q) am += mean6[q] * am_w[o * 6 + q];
            at[o] = fmaxf(am, 0.f) * fmaxf(at[o], 0.f);
        }
    } else {
#pragma unroll
        for (int o = 0; o < 32; ++o) at[o] = 0.f;
    }

    bool owner = live && !bound && (j == (int)s);
    unsigned end = s + c;   // interior segments: c exact (<=256), inside block
    unsigned* arow = (unsigned*)outMax + (size_t)r * 32;
    float4* ov = (float4*)(outMax + (size_t)r * 32);

    // ---- phase LO: cols 0..15 streamed to LDS (or atomicMax for boundary) ----
    if (live) {
#pragma unroll
        for (int o = 0; o < 16; ++o) {
            float v = af_b[o];
#pragma unroll
            for (int q = 0; q < 32; ++q) v += at[q] * af_w[o * 32 + q];
            if (bound) atomicMax(&arow[o], f2o(v));
            else buf[t][o] = v;
        }
    }
    __syncthreads();
    if (owner) {
        float vm[16];
#pragma unroll
        for (int o = 0; o < 16; ++o) vm[o] = buf[t][o];
        for (unsigned j2 = (unsigned)j + 1; j2 < end; ++j2) {
            int t2 = t + (int)(j2 - (unsigned)j);
#pragma unroll
            for (int o = 0; o < 16; ++o) vm[o] = fmaxf(vm[o], buf[t2][o]);
        }
#pragma unroll
        for (int k = 0; k < 4; ++k)
            ov[k] = make_float4(vm[4 * k], vm[4 * k + 1], vm[4 * k + 2], vm[4 * k + 3]);
    }
    __syncthreads();
    // ---- phase HI: cols 16..31 ----
    if (live) {
#pragma unroll
        for (int o = 0; o < 16; ++o) {
            float v = af_b[16 + o];
#pragma unroll
            for (int q = 0; q < 32; ++q) v += at[q] * af_w[(16 + o) * 32 + q];
            if (bound) atomicMax(&arow[16 + o], f2o(v));
            else buf[t][o] = v;
        }
    }
    __syncthreads();
    if (owner) {
        float vm[16];
#pragma unroll
        for (int o = 0; o < 16; ++o) vm[o] = buf[t][o];
        for (unsigned j2 = (unsigned)j + 1; j2 < end; ++j2) {
            int t2 = t + (int)(j2 - (unsigned)j);
#pragma unroll
            for (int o = 0; o < 16; ++o) vm[o] = fmaxf(vm[o], buf[t2][o]);
        }
#pragma unroll
        for (int k = 0; k < 4; ++k)
            ov[4 + k] = make_float4(vm[4 * k], vm[4 * k + 1], vm[4 * k + 2], vm[4 * k + 3]);
    }
}

// row-per-thread finalize: untransform boundary rows; zero pad rows (maxf + coords)
__global__ __launch_bounds__(256) void k_finrow(
    float* __restrict__ outMax, float* __restrict__ outCoord,
    const unsigned char* __restrict__ flags, const unsigned* __restrict__ U1p, int n) {
    int r = blockIdx.x * 256 + threadIdx.x;
    if (r >= n) return;
    unsigned U = *U1p;
    if ((unsigned)r >= U) {
        float4 z = make_float4(0.f, 0.f, 0.f, 0.f);
        float4* row = (float4*)(outMax + (size_t)r * 32);
#pragma unroll
        for (int k = 0; k < 8; ++k) row[k] = z;
        ((float4*)outCoord)[r] = z;
    } else if (flags[r]) {
        unsigned* urow = (unsigned*)outMax + (size_t)r * 32;
        float* frow = outMax + (size_t)r * 32;
#pragma unroll
        for (int o = 0; o < 32; ++o) frow[o] = o2f(urow[o]);
    }
}

// ---------------- host launch ----------------

extern "C" void kernel_launch(void* const* d_in, const int* in_sizes, int n_in,
                              void* d_out, int out_size, void* d_ws, size_t ws_size,
                              hipStream_t stream) {
    const float4* pc = (const float4*)d_in[0];
    const int* ind   = (const int*)d_in[1];
    const float* w05 = (const float*)d_in[2];
    const float* b05 = (const float*)d_in[3];
    const float* ww05 = (const float*)d_in[4];
    const float* wb05 = (const float*)d_in[5];
    const float* w1  = (const float*)d_in[6];
    const float* b1  = (const float*)d_in[7];
    const float* ww1 = (const float*)d_in[8];
    const float* wb1 = (const float*)d_in[9];
    const float* am_w = (const float*)d_in[10];
    const float* am_b = (const float*)d_in[11];
    const float* at_w = (const float*)d_in[12];
    const float* at_b = (const float*)d_in[13];
    const float* af_w = (const float*)d_in[14];
    const float* af_b = (const float*)d_in[15];

    int n = in_sizes[0] / 4;
    int B = in_sizes[1] - 1;

    int nW05 = B * (512 * 512 * 64 / 32);
    int nW1  = B * (256 * 256 * 32 / 32);
    int nB05 = (nW05 + 2047) / 2048;
    int nB1  = (nW1 + 2047) / 2048;
    int nCh  = (n + 2047) / 2048;

    size_t off = 0;
    char* base = (char*)d_ws;
    auto take = [&](size_t bytes) -> char* {
        char* p = base + off;
        off = (off + bytes + 255) & ~(size_t)255;
        return p;
    };

    // zero-init group (single contiguous memset)
    unsigned* mask05 = (unsigned*)take((size_t)nW05 * 4);
    unsigned* mask1  = (unsigned*)take((size_t)nW1 * 4);
    unsigned* cnt05  = (unsigned*)take((size_t)n * 4);
    unsigned* cnt1   = (unsigned*)take((size_t)n * 4);
    unsigned char* flags = (unsigned char*)take((size_t)n);
    size_t zeroBytes = off;

    unsigned* wp05   = (unsigned*)take((size_t)nW05 * 4);
    unsigned* wp1    = (unsigned*)take((size_t)nW1 * 4);
    unsigned* inv05  = (unsigned*)take((size_t)n * 4);
    unsigned* inv1   = (unsigned*)take((size_t)n * 4);
    unsigned* slot05 = (unsigned*)take((size_t)n * 4);
    unsigned* slot1  = (unsigned*)take((size_t)n * 4);
    unsigned* start05 = (unsigned*)take((size_t)n * 4);
    unsigned* start1  = (unsigned*)take((size_t)n * 4);
    uint4*    recA05  = (uint4*)take((size_t)n * 32);  // {p | r05,-,-,-}
    uint4*    recA1   = (uint4*)take((size_t)n * 32);  // {p | r1,r05,meta,-}
    float4*   mean05  = (float4*)take((size_t)n * 16);
    float4*   mean1   = (float4*)take((size_t)n * 16);
    unsigned short* mx05 = (unsigned short*)take((size_t)n * 32);  // bf16 [n][16]
    unsigned short* mx1  = (unsigned short*)take((size_t)n * 32);
    float*    atT     = (float*)take((size_t)2048 * 4);  // at_w transposed [64][32]
    unsigned* bsum05  = (unsigned*)take((size_t)nB05 * 4);
    unsigned* bpref05 = (unsigned*)take((size_t)nB05 * 4);
    unsigned* bsum1   = (unsigned*)take((size_t)nB1 * 4);
    unsigned* bpref1  = (unsigned*)take((size_t)nB1 * 4);
    unsigned* bsC05   = (unsigned*)take((size_t)nCh * 4);
    unsigned* bpC05   = (unsigned*)take((size_t)nCh * 4);
    unsigned* bsC1    = (unsigned*)take((size_t)nCh * 4);
    unsigned* bpC1    = (unsigned*)take((size_t)nCh * 4);
    unsigned* U1p     = (unsigned*)take(4);
    size_t total = off;

    if (ws_size < total) {
        fprintf(stderr, "kernel_launch: ws too small (%zu < %zu)\n", ws_size, total);
        return;
    }

    float* outMaxF = (float*)d_out;                      // [n,32]
    float* outCoord = (float*)d_out + (size_t)n * 32;    // [n,4]
    float* outInv = (float*)d_out + (size_t)n * 36;      // [n]

    hipMemsetAsync(d_ws, 0, zeroBytes, stream);

    int gpts = (n + 255) / 256;
    int nbb  = (gpts + 255) / 256;
    // weight transpose (no dependencies; overlaps the rest)
    k_wtr<<<8, 256, 0, stream>>>(at_w, atT);
    // unique-rank machinery (both scales per launch)
    k_bits<<<gpts, 256, 0, stream>>>(pc, ind, B, n, mask05, mask1);
    k_chunk2<<<nB05 + nB1, 256, 0, stream>>>(mask05, bsum05, nW05, nB05,
                                             mask1, bsum1, nW1);
    k_scan2<<<2, 1024, 0, stream>>>(bsum05, bpref05, nullptr, nB05,
                                    bsum1, bpref1, U1p, nB1);
    k_wpref2<<<nB05 + nB1, 256, 0, stream>>>(mask05, bpref05, wp05, nW05, nB05,
                                             mask1, bpref1, wp1, nW1);
    // ranks + counts + slots (one atomic per point per scale)
    k_rank<<<gpts, 256, 0, stream>>>(pc, ind, B, n, mask05, wp05, mask1, wp1,
                                     inv05, inv1, cnt05, cnt1, slot05, slot1,
                                     outCoord, outInv);
    // CSR starts
    k_chunku2<<<2 * nCh, 256, 0, stream>>>(cnt05, bsC05, cnt1, bsC1, n, nCh);
    k_scan2<<<2, 1024, 0, stream>>>(bsC05, bpC05, nullptr, nCh,
                                    bsC1, bpC1, nullptr, nCh);
    k_eprefu2<<<2 * nCh, 256, 0, stream>>>(cnt05, bpC05, start05,
                                           cnt1, bpC1, start1, n, nCh);
    // counting-sort scatter of 32B point records (plain stores)
    k_slot<<<gpts, 256, 0, stream>>>(pc, inv05, inv1, slot05, slot1,
                                     start05, start1, cnt1, recA05, recA1, n);
    // per-voxel means (both scales) + boundary flags/binit (third range)
    k_segmean2<<<2 * gpts + nbb, 256, 0, stream>>>(recA05, start05, cnt05, mean05,
                                                   recA1, start1, cnt1, mean1,
                                                   flags, (unsigned*)outMaxF, n, gpts);
    // per-voxel mx (bf16), both scales in one launch
    k_segmx2<<<2 * gpts, 256, 0, stream>>>(recA05, start05, cnt05, mean05,
                                           w05, b05, ww05, wb05, mx05,
                                           recA1, start1, cnt1, mean1,
                                           w1, b1, ww1, wb1, mx1, n, gpts);
    // fused pipeline + two-phase segmented max (transposed at_w)
    k_val<<<gpts, 256, 0, stream>>>(recA1,
                                    mean05, mx05, mean1, mx1,
                                    w05, b05, ww05, wb05, w1, b1, ww1, wb1,
                                    am_w, am_b, atT, at_b, af_w, af_b,
                                    outMaxF, n);
    // untransform boundary rows + zero pad rows (row-per-thread)
    k_finrow<<<gpts, 256, 0, stream>>>(outMaxF, outCoord, flags, U1p, n);

    (void)n_in; (void)out_size;
}

// Round 10
// 702.205 us; speedup vs baseline: 2.2372x; 1.0477x over previous
//
#include <hip/hip_runtime.h>
#include <cstdint>
#include <cstdio>

// ---------------- device helpers ----------------

struct Coords { int xi, yi, zi; };

// EXACT replication of reference quantization (all f32 ops, truncating cast)
__device__ __forceinline__ Coords quantc(float x, float y, float z, float sx, float sy, float sz) {
    Coords c;
    c.xi = (int)(((x - 0.0f)  / 51.2f) * sx);
    c.yi = (int)(((y + 25.6f) / 51.2f) * sy);
    c.zi = (int)(((z + 2.0f)  / 6.4f)  * sz);
    return c;
}

__device__ __forceinline__ int batch_of(int i, const int* __restrict__ ind, int B) {
    int bt = 0;
    for (int b = 1; b < B; ++b) if (i >= ind[b]) bt = b;
    return bt;
}

// order-preserving float<->uint transform for atomicMax on signed floats
__device__ __forceinline__ unsigned f2o(float f) {
    unsigned u = __float_as_uint(f);
    return (u & 0x80000000u) ? ~u : (u | 0x80000000u);
}
__device__ __forceinline__ float o2f(unsigned u) {
    return (u & 0x80000000u) ? __uint_as_float(u ^ 0x80000000u) : __uint_as_float(~u);
}
#define NEG_O 0x007FFFFFu   // f2o(-inf)

// bf16 helpers (RTNE)
__device__ __forceinline__ unsigned short f2bf(float x) {
    unsigned u = __float_as_uint(x);
    unsigned r = (u + 0x7FFFu + ((u >> 16) & 1u)) >> 16;
    return (unsigned short)r;
}
__device__ __forceinline__ float bf2f(unsigned h) {
    return __uint_as_float(h << 16);
}

// x[16] = (feat@W.T + b) * (mean@Ww.T + wb);  mean6 out = [mm, gmm]
__device__ __forceinline__ void compute_x16(
    float px, float py, float pz, float pw,
    float mx_, float my_, float mz_, Coords c,
    const float* __restrict__ W, const float* __restrict__ Bv,
    const float* __restrict__ Ww, const float* __restrict__ Wb,
    float* __restrict__ x, float* __restrict__ mean6) {
    float gx = px - (((float)c.xi + 0.5f) * 0.2f + 0.0f);
    float gy = py - (((float)c.yi + 0.5f) * 0.2f + (-25.6f));
    float gz = pz - (((float)c.zi + 0.5f) * 0.2f + (-2.0f));
    float mmx = px - mx_, mmy = py - my_, mmz = pz - mz_;
    float feat[10] = {px, py, pz, pw, mmx, mmy, mmz, gx, gy, gz};
    float mean[6]  = {mmx, mmy, mmz, gx, gy, gz};
#pragma unroll
    for (int j = 0; j < 6; ++j) mean6[j] = mean[j];
#pragma unroll
    for (int o = 0; o < 16; ++o) {
        float a = Bv[o];
#pragma unroll
        for (int j = 0; j < 10; ++j) a += feat[j] * W[o * 10 + j];
        float g = Wb[o];
#pragma unroll
        for (int j = 0; j < 6; ++j) g += mean[j] * Ww[o * 6 + j];
        x[o] = a * g;
    }
}

// ---------------- bitmask unique-rank machinery ----------------

__global__ __launch_bounds__(256) void k_bits(
    const float4* __restrict__ pc, const int* __restrict__ ind, int B, int n,
    unsigned* __restrict__ mask05, unsigned* __restrict__ mask1) {
    int i = blockIdx.x * 256 + threadIdx.x;
    if (i >= n) return;
    float4 p = pc[i];
    int bt = batch_of(i, ind, B);
    Coords c05 = quantc(p.x, p.y, p.z, 512.f, 512.f, 64.f);
    Coords c1  = quantc(p.x, p.y, p.z, 256.f, 256.f, 32.f);
    int lid05 = ((bt * 512 + c05.xi) * 512 + c05.yi) * 64 + c05.zi;
    int lid1  = ((bt * 256 + c1.xi)  * 256 + c1.yi)  * 32 + c1.zi;
    atomicOr(&mask05[lid05 >> 5], 1u << (lid05 & 31));
    atomicOr(&mask1[lid1 >> 5],  1u << (lid1 & 31));
}

// weight transposes for scalar-load batching + float2 output-pairing:
//   atT[c][o] = at_w[o][c]  (64x32)  — round-9 win (+30% on k_val)
//   afT[q][o] = af_w[o][q]  (32x32)
//   amT[q][o] = am_w[o][q]  (6x32)
// Paired-o weights land adjacent -> 64-bit operands for v_pk_fma_f32.
__global__ __launch_bounds__(256) void k_wtr(
    const float* __restrict__ at_w, const float* __restrict__ af_w,
    const float* __restrict__ am_w,
    float* __restrict__ atT, float* __restrict__ afT, float* __restrict__ amT) {
    int i = blockIdx.x * 256 + threadIdx.x;
    if (i < 2048) {
        int o = i >> 6, c = i & 63;
        atT[c * 32 + o] = at_w[i];
    } else if (i < 3072) {
        int j = i - 2048; int o = j >> 5, q = j & 31;
        afT[q * 32 + o] = af_w[j];
    } else if (i < 3264) {
        int j = i - 3072; int o = j / 6, q = j % 6;
        amT[q * 32 + o] = am_w[j];
    }
}

// merged popc-chunk over BOTH masks (blockIdx split)
__global__ __launch_bounds__(256) void k_chunk2(
    const unsigned* __restrict__ maskA, unsigned* __restrict__ bsumA, int nWA, int nBA,
    const unsigned* __restrict__ maskB, unsigned* __restrict__ bsumB, int nWB) {
    const unsigned* mask; unsigned* bsum; int nW, blk;
    if ((int)blockIdx.x < nBA) { mask = maskA; bsum = bsumA; nW = nWA; blk = blockIdx.x; }
    else { mask = maskB; bsum = bsumB; nW = nWB; blk = blockIdx.x - nBA; }
    int t = threadIdx.x;
    int base = blk * 2048 + t;
    unsigned tot = 0;
#pragma unroll
    for (int k = 0; k < 8; ++k) {
        int w = base + k * 256;
        if (w < nW) tot += __popc(mask[w]);
    }
    __shared__ unsigned s[256];
    s[t] = tot;
    __syncthreads();
    for (int off = 128; off > 0; off >>= 1) {
        if (t < off) s[t] += s[t + off];
        __syncthreads();
    }
    if (t == 0) bsum[blk] = s[0];
}

// merged chunk-sum over both cnt arrays
__global__ __launch_bounds__(256) void k_chunku2(
    const unsigned* __restrict__ cntA, unsigned* __restrict__ bsumA,
    const unsigned* __restrict__ cntB, unsigned* __restrict__ bsumB,
    int nElem, int nCh) {
    const unsigned* val; unsigned* bsum; int blk;
    if ((int)blockIdx.x < nCh) { val = cntA; bsum = bsumA; blk = blockIdx.x; }
    else { val = cntB; bsum = bsumB; blk = blockIdx.x - nCh; }
    int t = threadIdx.x;
    int base = blk * 2048 + t;
    unsigned tot = 0;
#pragma unroll
    for (int k = 0; k < 8; ++k) {
        int w = base + k * 256;
        if (w < nElem) tot += val[w];
    }
    __shared__ unsigned s[256];
    s[t] = tot;
    __syncthreads();
    for (int off = 128; off > 0; off >>= 1) {
        if (t < off) s[t] += s[t + off];
        __syncthreads();
    }
    if (t == 0) bsum[blk] = s[0];
}

// merged single-block scans: block 0 does set A, block 1 set B
__global__ __launch_bounds__(1024) void k_scan2(
    const unsigned* __restrict__ bsumA, unsigned* __restrict__ bprefA,
    unsigned* __restrict__ UoutA, int nA,
    const unsigned* __restrict__ bsumB, unsigned* __restrict__ bprefB,
    unsigned* __restrict__ UoutB, int nB) {
    const unsigned* bsum; unsigned* bpref; unsigned* Uout; int nBn;
    if (blockIdx.x == 0) { bsum = bsumA; bpref = bprefA; Uout = UoutA; nBn = nA; }
    else { bsum = bsumB; bpref = bprefB; Uout = UoutB; nBn = nB; }
    __shared__ unsigned s[1024];
    int t = threadIdx.x;
    int ipt = (nBn + 1023) >> 10;
    unsigned tot = 0;
    for (int k = 0; k < ipt; ++k) {
        int e = t * ipt + k;
        if (e < nBn) tot += bsum[e];
    }
    s[t] = tot;
    __syncthreads();
    for (int off = 1; off < 1024; off <<= 1) {
        unsigned v = 0;
        if (t >= off) v = s[t - off];
        __syncthreads();
        if (t >= off) s[t] += v;
        __syncthreads();
    }
    unsigned run = s[t] - tot;  // exclusive
    for (int k = 0; k < ipt; ++k) {
        int e = t * ipt + k;
        if (e < nBn) { bpref[e] = run; run += bsum[e]; }
    }
    if (t == 1023 && Uout) *Uout = s[1023];
}

// merged per-word prefix over both masks
__global__ __launch_bounds__(256) void k_wpref2(
    const unsigned* __restrict__ maskA, const unsigned* __restrict__ bprefA,
    unsigned* __restrict__ wprefA, int nWA, int nBA,
    const unsigned* __restrict__ maskB, const unsigned* __restrict__ bprefB,
    unsigned* __restrict__ wprefB, int nWB) {
    const unsigned* mask; const unsigned* bpref; unsigned* wpref; int nW, blk;
    if ((int)blockIdx.x < nBA) { mask = maskA; bpref = bprefA; wpref = wprefA; nW = nWA; blk = blockIdx.x; }
    else { mask = maskB; bpref = bprefB; wpref = wprefB; nW = nWB; blk = blockIdx.x - nBA; }
    int t = threadIdx.x;
    int base = blk * 2048 + t * 8;
    unsigned p[8];
    unsigned tot = 0;
#pragma unroll
    for (int k = 0; k < 8; ++k) {
        int w = base + k;
        p[k] = (w < nW) ? __popc(mask[w]) : 0u;
        tot += p[k];
    }
    __shared__ unsigned s[256];
    s[t] = tot;
    __syncthreads();
    for (int off = 1; off < 256; off <<= 1) {
        unsigned v = 0;
        if (t >= off) v = s[t - off];
        __syncthreads();
        if (t >= off) s[t] += v;
        __syncthreads();
    }
    unsigned run = bpref[blk] + (s[t] - tot);
#pragma unroll
    for (int k = 0; k < 8; ++k) {
        int w = base + k;
        if (w < nW) { wpref[w] = run; run += p[k]; }
    }
}

// merged element prefix over both cnt arrays -> start offsets
__global__ __launch_bounds__(256) void k_eprefu2(
    const unsigned* __restrict__ cntA, const unsigned* __restrict__ bprefA,
    unsigned* __restrict__ startA,
    const unsigned* __restrict__ cntB, const unsigned* __restrict__ bprefB,
    unsigned* __restrict__ startB,
    int nElem, int nCh) {
    const unsigned* val; const unsigned* bpref; unsigned* epref; int blk;
    if ((int)blockIdx.x < nCh) { val = cntA; bpref = bprefA; epref = startA; blk = blockIdx.x; }
    else { val = cntB; bpref = bprefB; epref = startB; blk = blockIdx.x - nCh; }
    int t = threadIdx.x;
    int base = blk * 2048 + t * 8;
    unsigned p[8];
    unsigned tot = 0;
#pragma unroll
    for (int k = 0; k < 8; ++k) {
        int w = base + k;
        p[k] = (w < nElem) ? val[w] : 0u;
        tot += p[k];
    }
    __shared__ unsigned s[256];
    s[t] = tot;
    __syncthreads();
    for (int off = 1; off < 256; off <<= 1) {
        unsigned v = 0;
        if (t >= off) v = s[t - off];
        __syncthreads();
        if (t >= off) s[t] += v;
        __syncthreads();
    }
    unsigned run = bpref[blk] + (s[t] - tot);
#pragma unroll
    for (int k = 0; k < 8; ++k) {
        int w = base + k;
        if (w < nElem) { epref[w] = run; run += p[k]; }
    }
}

// ---------------- point passes ----------------

// ranks + counts + slots. ONE scattered atomic per point per scale — the
// atomicAdd's return value IS the slot. outCoord written once per voxel.
__global__ __launch_bounds__(256) void k_rank(
    const float4* __restrict__ pc, const int* __restrict__ ind, int B, int n,
    const unsigned* __restrict__ mask05, const unsigned* __restrict__ wp05,
    const unsigned* __restrict__ mask1, const unsigned* __restrict__ wp1,
    unsigned* __restrict__ inv05, unsigned* __restrict__ inv1,
    unsigned* __restrict__ cnt05, unsigned* __restrict__ cnt1,
    unsigned* __restrict__ slot05, unsigned* __restrict__ slot1,
    float* __restrict__ outCoord, float* __restrict__ outInv) {
    int i = blockIdx.x * 256 + threadIdx.x;
    if (i >= n) return;
    float4 p = pc[i];
    int bt = batch_of(i, ind, B);
    Coords c05 = quantc(p.x, p.y, p.z, 512.f, 512.f, 64.f);
    Coords c1  = quantc(p.x, p.y, p.z, 256.f, 256.f, 32.f);
    int lid05 = ((bt * 512 + c05.xi) * 512 + c05.yi) * 64 + c05.zi;
    int lid1  = ((bt * 256 + c1.xi)  * 256 + c1.yi)  * 32 + c1.zi;

    unsigned w = (unsigned)lid05 >> 5, b = (unsigned)lid05 & 31u;
    unsigned r05 = wp05[w] + __popc(mask05[w] & ((1u << b) - 1u));
    w = (unsigned)lid1 >> 5; b = (unsigned)lid1 & 31u;
    unsigned r1 = wp1[w] + __popc(mask1[w] & ((1u << b) - 1u));

    inv05[i] = r05;
    inv1[i] = r1;
    outInv[i] = (float)r1;

    slot05[i] = atomicAdd(&cnt05[r05], 1u);
    unsigned sl1 = atomicAdd(&cnt1[r1], 1u);
    slot1[i] = sl1;
    if (sl1 == 0u)
        ((float4*)outCoord)[r1] = make_float4((float)bt, (float)c1.xi, (float)c1.yi, (float)c1.zi);
}

// counting-sort scatter of 32B point records into CSR order.
// recA05[2j]={p}, recA05[2j+1]={r05,-,-,-}
// recA1 [2j]={p}, recA1 [2j+1]={r1, r05, meta,-}; meta = start1 | min(cnt1,257)<<23
__global__ __launch_bounds__(256) void k_slot(
    const float4* __restrict__ pc,
    const unsigned* __restrict__ inv05, const unsigned* __restrict__ inv1,
    const unsigned* __restrict__ slot05, const unsigned* __restrict__ slot1,
    const unsigned* __restrict__ start05, const unsigned* __restrict__ start1,
    const unsigned* __restrict__ cnt1,
    uint4* __restrict__ recA05, uint4* __restrict__ recA1, int n) {
    int i = blockIdx.x * 256 + threadIdx.x;
    if (i >= n) return;
    float4 p = pc[i];
    unsigned r05 = inv05[i], r1 = inv1[i];
    unsigned p05 = start05[r05] + slot05[i];
    unsigned s1 = start1[r1];
    unsigned p1  = s1 + slot1[i];
    unsigned c1 = cnt1[r1];
    unsigned cm = c1 < 257u ? c1 : 257u;
    unsigned meta = s1 | (cm << 23);
    uint4 pw = *(const uint4*)&p;
    recA05[(size_t)p05 * 2]     = pw;
    recA05[(size_t)p05 * 2 + 1] = make_uint4(r05, 0u, 0u, 0u);
    recA1[(size_t)p1 * 2]       = pw;
    recA1[(size_t)p1 * 2 + 1]   = make_uint4(r1, r05, meta, 0u);
}

// merged: wave-level segmented mean over CSR records for BOTH scales, plus the
// boundary-flag/binit pass as a third blockIdx range. Points read coalesced.
__global__ __launch_bounds__(256) void k_segmean2(
    const uint4* __restrict__ recA05, const unsigned* __restrict__ start05,
    const unsigned* __restrict__ cnt05, float4* __restrict__ mean05,
    const uint4* __restrict__ recA1, const unsigned* __restrict__ start1,
    const unsigned* __restrict__ cnt1, float4* __restrict__ mean1,
    unsigned char* __restrict__ flags, unsigned* __restrict__ outMaxU,
    int n, int gpts) {
    // third range: boundary-segment flags + atomicMax row init
    if ((int)blockIdx.x >= 2 * gpts) {
        int blk3 = blockIdx.x - 2 * gpts;
        int b = blk3 * 256 + threadIdx.x + 1;
        if (b >= gpts) return;
        int j = b * 256;
        if (j >= n) return;
        unsigned r = recA1[(size_t)j * 2 + 1].x;
        if (start1[r] < (unsigned)j) {
            flags[r] = 1;
            unsigned* row = outMaxU + (size_t)r * 32;
#pragma unroll
            for (int o = 0; o < 32; ++o) row[o] = NEG_O;
        }
        return;
    }
    const uint4* recA; const unsigned* start; const unsigned* cnt;
    float4* meanOut; int blk;
    if ((int)blockIdx.x < gpts) {
        recA = recA05; start = start05; cnt = cnt05; meanOut = mean05; blk = blockIdx.x;
    } else {
        recA = recA1; start = start1; cnt = cnt1; meanOut = mean1; blk = blockIdx.x - gpts;
    }
    int j = blk * 256 + threadIdx.x;
    int lane = threadIdx.x & 63;
    bool live = j < n;
    unsigned r = 0xFFFFFFFFu;
    float sx = 0.f, sy = 0.f, sz = 0.f;
    if (live) {
        float4 p = *(const float4*)&recA[(size_t)j * 2];
        r = recA[(size_t)j * 2 + 1].x;
        sx = p.x; sy = p.y; sz = p.z;
    }
#pragma unroll
    for (int d = 1; d < 64; d <<= 1) {
        unsigned rn = (unsigned)__shfl_down((int)r, d);
        float ax = __shfl_down(sx, d);
        float ay = __shfl_down(sy, d);
        float az = __shfl_down(sz, d);
        bool ok = (lane + d) < 64 && rn == r;
        if (ok) { sx += ax; sy += ay; sz += az; }
    }
    if (!live) return;
    if (j != (int)start[r]) return;
    unsigned c = cnt[r];
    unsigned end = j + c;
    unsigned waveEnd = ((unsigned)j & ~63u) + 64u;
    for (unsigned j2 = waveEnd; j2 < end; ++j2) {
        float4 q = *(const float4*)&recA[(size_t)j2 * 2];
        sx += q.x; sy += q.y; sz += q.z;
    }
    float cf = (float)c;
    meanOut[r] = make_float4(sx / cf, sy / cf, sz / cf, 0.f);
}

// merged block-level LDS segmented max of x16 for BOTH scales (blockIdx split)
__global__ __launch_bounds__(256) void k_segmx2(
    const uint4* __restrict__ recA05, const unsigned* __restrict__ start05,
    const unsigned* __restrict__ cnt05, const float4* __restrict__ mean05,
    const float* __restrict__ w05, const float* __restrict__ b05,
    const float* __restrict__ ww05, const float* __restrict__ wb05,
    unsigned short* __restrict__ mx05,
    const uint4* __restrict__ recA1, const unsigned* __restrict__ start1,
    const unsigned* __restrict__ cnt1, const float4* __restrict__ mean1,
    const float* __restrict__ w1, const float* __restrict__ b1,
    const float* __restrict__ ww1, const float* __restrict__ wb1,
    unsigned short* __restrict__ mx1,
    int n, int gpts) {
    const uint4* recA; const unsigned* start; const unsigned* cnt;
    const float4* meanIn; const float* W; const float* Bv; const float* Ww;
    const float* Wb; unsigned short* mxOut; int blk;
    float sx_, sy_, sz_;
    if ((int)blockIdx.x < gpts) {
        recA = recA05; start = start05; cnt = cnt05; meanIn = mean05;
        W = w05; Bv = b05; Ww = ww05; Wb = wb05; mxOut = mx05;
        sx_ = 512.f; sy_ = 512.f; sz_ = 64.f; blk = blockIdx.x;
    } else {
        recA = recA1; start = start1; cnt = cnt1; meanIn = mean1;
        W = w1; Bv = b1; Ww = ww1; Wb = wb1; mxOut = mx1;
        sx_ = 256.f; sy_ = 256.f; sz_ = 32.f; blk = blockIdx.x - gpts;
    }
    __shared__ float buf[256][17];
    int t = threadIdx.x;
    int j = blk * 256 + t;
    bool live = j < n;
    unsigned r = 0;
    float x[16], d6[6];
    if (live) {
        float4 p = *(const float4*)&recA[(size_t)j * 2];
        r = recA[(size_t)j * 2 + 1].x;
        float4 mv = meanIn[r];
        Coords cc = quantc(p.x, p.y, p.z, sx_, sy_, sz_);
        compute_x16(p.x, p.y, p.z, p.w, mv.x, mv.y, mv.z, cc, W, Bv, Ww, Wb, x, d6);
    } else {
#pragma unroll
        for (int o = 0; o < 16; ++o) x[o] = 0.f;
    }
#pragma unroll
    for (int o = 0; o < 16; ++o) buf[t][o] = x[o];
    __syncthreads();
    if (!live || j != (int)start[r]) return;
    unsigned c = cnt[r];
    unsigned end = j + c;
    unsigned blockEnd = ((unsigned)blk + 1u) * 256u;
    unsigned inEnd = end < blockEnd ? end : blockEnd;
    for (unsigned j2 = j + 1; j2 < inEnd; ++j2) {
        int t2 = t + (int)(j2 - (unsigned)j);
#pragma unroll
        for (int o = 0; o < 16; ++o) x[o] = fmaxf(x[o], buf[t2][o]);
    }
    float4 mv = meanIn[r];
    for (unsigned j2 = blockEnd; j2 < end; ++j2) {
        float4 q = *(const float4*)&recA[(size_t)j2 * 2];
        Coords cc = quantc(q.x, q.y, q.z, sx_, sy_, sz_);
        float x2[16];
        compute_x16(q.x, q.y, q.z, q.w, mv.x, mv.y, mv.z, cc, W, Bv, Ww, Wb, x2, d6);
#pragma unroll
        for (int o = 0; o < 16; ++o) x[o] = fmaxf(x[o], x2[o]);
    }
    unsigned pk[8];
#pragma unroll
    for (int k = 0; k < 8; ++k)
        pk[k] = (unsigned)f2bf(x[2 * k]) | ((unsigned)f2bf(x[2 * k + 1]) << 16);
    uint4* mr = (uint4*)(mxOut + (size_t)r * 16);
    mr[0] = make_uint4(pk[0], pk[1], pk[2], pk[3]);
    mr[1] = make_uint4(pk[4], pk[5], pk[6], pk[7]);
}

// fused per-point pipeline + two-phase in-block segmented max.
// All matvec loops use float2 OUTPUT-PAIRING: accumulate (at[2k],at[2k+1])
// as float2 with paired weights adjacent in memory (atT/afT/amT transposed
// layouts) -> eligible for v_pk_fma_f32 (2 f32 FMA/inst; the only way to
// f32 issue peak). Per-output accumulation ORDER unchanged -> bit-exact.
// (256,3): round-4 lesson. Weights from global (round-8 lesson).
__global__ __launch_bounds__(256, 3) void k_val(
    const uint4* __restrict__ recA1,
    const float4* __restrict__ mean05, const unsigned short* __restrict__ mx05,
    const float4* __restrict__ mean1, const unsigned short* __restrict__ mx1,
    const float* __restrict__ w05, const float* __restrict__ b05,
    const float* __restrict__ ww05, const float* __restrict__ wb05,
    const float* __restrict__ w1g, const float* __restrict__ b1g,
    const float* __restrict__ ww1, const float* __restrict__ wb1,
    const float* __restrict__ amT, const float* __restrict__ am_b,
    const float* __restrict__ atT, const float* __restrict__ at_b,
    const float* __restrict__ afT, const float* __restrict__ af_b,
    float* __restrict__ outMax, int n) {
    __shared__ float buf[256][17];
    int t = threadIdx.x;
    int j = blockIdx.x * 256 + t;
    bool live = j < n;
    unsigned r = 0, s = 0, c = 0;
    bool bound = false;
    float2 at2[16];
    if (live) {
        uint4 pw4 = recA1[(size_t)j * 2];
        float4 p = *(const float4*)&pw4;
        uint4 mw = recA1[(size_t)j * 2 + 1];
        r = mw.x;
        unsigned r05 = mw.y;
        unsigned meta = mw.z;
        s = meta & 0x7FFFFFu;
        c = meta >> 23;                        // min(cnt,257)
        bound = (c > 256u) || ((s >> 8) != ((s + c - 1) >> 8));

#pragma unroll
        for (int k = 0; k < 16; ++k) at2[k] = ((const float2*)at_b)[k];

        // mx1 row (bf16) -> cols 48..63
        {
            const uint4* m4 = (const uint4*)(mx1 + (size_t)r * 16);
            uint4 a = m4[0], b2 = m4[1];
            unsigned pw[8] = {a.x, a.y, a.z, a.w, b2.x, b2.y, b2.z, b2.w};
#pragma unroll
            for (int kk = 0; kk < 8; ++kk) {
                float e0 = bf2f(pw[kk] & 0xFFFFu);
                float e1 = bf2f(pw[kk] >> 16);
                const float2* wc0 = (const float2*)(atT + (48 + 2 * kk) * 32);
                const float2* wc1 = (const float2*)(atT + (49 + 2 * kk) * 32);
#pragma unroll
                for (int k = 0; k < 16; ++k) {
                    float2 w0 = wc0[k], w1 = wc1[k];
                    at2[k].x += e0 * w0.x + e1 * w1.x;
                    at2[k].y += e0 * w0.y + e1 * w1.y;
                }
            }
        }
        // mx05 row (bf16) -> cols 16..31
        {
            const uint4* m4 = (const uint4*)(mx05 + (size_t)r05 * 16);
            uint4 a = m4[0], b2 = m4[1];
            unsigned pw[8] = {a.x, a.y, a.z, a.w, b2.x, b2.y, b2.z, b2.w};
#pragma unroll
            for (int kk = 0; kk < 8; ++kk) {
                float e0 = bf2f(pw[kk] & 0xFFFFu);
                float e1 = bf2f(pw[kk] >> 16);
                const float2* wc0 = (const float2*)(atT + (16 + 2 * kk) * 32);
                const float2* wc1 = (const float2*)(atT + (17 + 2 * kk) * 32);
#pragma unroll
                for (int k = 0; k < 16; ++k) {
                    float2 w0 = wc0[k], w1 = wc1[k];
                    at2[k].x += e0 * w0.x + e1 * w1.x;
                    at2[k].y += e0 * w0.y + e1 * w1.y;
                }
            }
        }
        // x05 -> cols 0..15: fused compute+consume
        {
            float4 mv = mean05[r05];
            Coords cc = quantc(p.x, p.y, p.z, 512.f, 512.f, 64.f);
            float gx = p.x - (((float)cc.xi + 0.5f) * 0.1f + 0.0f);
            float gy = p.y - (((float)cc.yi + 0.5f) * 0.1f + (-25.6f));
            float gz = p.z - (((float)cc.zi + 0.5f) * 0.1f + (-2.0f));
            float mmx = p.x - mv.x, mmy = p.y - mv.y, mmz = p.z - mv.z;
            float feat[10] = {p.x, p.y, p.z, p.w, mmx, mmy, mmz, gx, gy, gz};
#pragma unroll
            for (int jj = 0; jj < 16; ++jj) {
                float a_ = b05[jj];
#pragma unroll
                for (int q = 0; q < 10; ++q) a_ += feat[q] * w05[jj * 10 + q];
                float g_ = wb05[jj];
#pragma unroll
                for (int q = 0; q < 6; ++q) g_ += feat[4 + q] * ww05[jj * 6 + q];
                float x_ = a_ * g_;
                const float2* wc = (const float2*)(atT + jj * 32);
#pragma unroll
                for (int k = 0; k < 16; ++k) {
                    float2 w0 = wc[k];
                    at2[k].x += x_ * w0.x;
                    at2[k].y += x_ * w0.y;
                }
            }
        }
        float mean6[6];
        // x1 -> cols 32..47 (keeps mean6 for am)
        {
            float4 mv = mean1[r];
            Coords cc = quantc(p.x, p.y, p.z, 256.f, 256.f, 32.f);
            float gx = p.x - (((float)cc.xi + 0.5f) * 0.2f + 0.0f);
            float gy = p.y - (((float)cc.yi + 0.5f) * 0.2f + (-25.6f));
            float gz = p.z - (((float)cc.zi + 0.5f) * 0.2f + (-2.0f));
            float mmx = p.x - mv.x, mmy = p.y - mv.y, mmz = p.z - mv.z;
            float feat[10] = {p.x, p.y, p.z, p.w, mmx, mmy, mmz, gx, gy, gz};
            mean6[0] = mmx; mean6[1] = mmy; mean6[2] = mmz;
            mean6[3] = gx;  mean6[4] = gy;  mean6[5] = gz;
#pragma unroll
            for (int jj = 0; jj < 16; ++jj) {
                float a_ = b1g[jj];
#pragma unroll
                for (int q = 0; q < 10; ++q) a_ += feat[q] * w1g[jj * 10 + q];
                float g_ = wb1[jj];
#pragma unroll
                for (int q = 0; q < 6; ++q) g_ += feat[4 + q] * ww1[jj * 6 + q];
                float x_ = a_ * g_;
                const float2* wc = (const float2*)(atT + (32 + jj) * 32);
#pragma unroll
                for (int k = 0; k < 16; ++k) {
                    float2 w0 = wc[k];
                    at2[k].x += x_ * w0.x;
                    at2[k].y += x_ * w0.y;
                }
            }
        }
        // h = relu(am)*relu(at), paired
        {
            float2 am2[16];
#pragma unroll
            for (int k = 0; k < 16; ++k) am2[k] = ((const float2*)am_b)[k];
#pragma unroll
            for (int q = 0; q < 6; ++q) {
                float m = mean6[q];
                const float2* wc = (const float2*)(amT + q * 32);
#pragma unroll
                for (int k = 0; k < 16; ++k) {
                    float2 w0 = wc[k];
                    am2[k].x += m * w0.x;
                    am2[k].y += m * w0.y;
                }
            }
#pragma unroll
            for (int k = 0; k < 16; ++k) {
                at2[k].x = fmaxf(am2[k].x, 0.f) * fmaxf(at2[k].x, 0.f);
                at2[k].y = fmaxf(am2[k].y, 0.f) * fmaxf(at2[k].y, 0.f);
            }
        }
    } else {
#pragma unroll
        for (int k = 0; k < 16; ++k) at2[k] = make_float2(0.f, 0.f);
    }

    float ats[32];
#pragma unroll
    for (int k = 0; k < 16; ++k) { ats[2 * k] = at2[k].x; ats[2 * k + 1] = at2[k].y; }

    bool owner = live && !bound && (j == (int)s);
    unsigned end = s + c;   // interior segments: c exact (<=256), inside block
    unsigned* arow = (unsigned*)outMax + (size_t)r * 32;
    float4* ov = (float4*)(outMax + (size_t)r * 32);

    // ---- phase LO: cols 0..15 streamed to LDS (or atomicMax for boundary) ----
    if (live) {
#pragma unroll
        for (int k = 0; k < 8; ++k) {
            float2 v2 = ((const float2*)af_b)[k];
#pragma unroll
            for (int q = 0; q < 32; ++q) {
                float aq = ats[q];
                float2 w2 = ((const float2*)(afT + q * 32))[k];
                v2.x += aq * w2.x;
                v2.y += aq * w2.y;
            }
            if (bound) {
                atomicMax(&arow[2 * k], f2o(v2.x));
                atomicMax(&arow[2 * k + 1], f2o(v2.y));
            } else {
                buf[t][2 * k] = v2.x;
                buf[t][2 * k + 1] = v2.y;
            }
        }
    }
    __syncthreads();
    if (owner) {
        float vm[16];
#pragma unroll
        for (int o = 0; o < 16; ++o) vm[o] = buf[t][o];
        for (unsigned j2 = (unsigned)j + 1; j2 < end; ++j2) {
            int t2 = t + (int)(j2 - (unsigned)j);
#pragma unroll
            for (int o = 0; o < 16; ++o) vm[o] = fmaxf(vm[o], buf[t2][o]);
        }
#pragma unroll
        for (int k = 0; k < 4; ++k)
            ov[k] = make_float4(vm[4 * k], vm[4 * k + 1], vm[4 * k + 2], vm[4 * k + 3]);
    }
    __syncthreads();
    // ---- phase HI: cols 16..31 ----
    if (live) {
#pragma unroll
        for (int k = 8; k < 16; ++k) {
            float2 v2 = ((const float2*)af_b)[k];
#pragma unroll
            for (int q = 0; q < 32; ++q) {
                float aq = ats[q];
                float2 w2 = ((const float2*)(afT + q * 32))[k];
                v2.x += aq * w2.x;
                v2.y += aq * w2.y;
            }
            if (bound) {
                atomicMax(&arow[2 * k], f2o(v2.x));
                atomicMax(&arow[2 * k + 1], f2o(v2.y));
            } else {
                buf[t][2 * (k - 8)] = v2.x;
                buf[t][2 * (k - 8) + 1] = v2.y;
            }
        }
    }
    __syncthreads();
    if (owner) {
        float vm[16];
#pragma unroll
        for (int o = 0; o < 16; ++o) vm[o] = buf[t][o];
        for (unsigned j2 = (unsigned)j + 1; j2 < end; ++j2) {
            int t2 = t + (int)(j2 - (unsigned)j);
#pragma unroll
            for (int o = 0; o < 16; ++o) vm[o] = fmaxf(vm[o], buf[t2][o]);
        }
#pragma unroll
        for (int k = 0; k < 4; ++k)
            ov[4 + k] = make_float4(vm[4 * k], vm[4 * k + 1], vm[4 * k + 2], vm[4 * k + 3]);
    }
}

// coalesced finalize: one float4 per thread (idx = r*8 + k). Round-9 note:
// previous row-per-thread version issued stride-128B stores (uncoalesced).
__global__ __launch_bounds__(256) void k_finrow(
    float* __restrict__ outMax, float* __restrict__ outCoord,
    const unsigned char* __restrict__ flags, const unsigned* __restrict__ U1p, int n) {
    int idx = blockIdx.x * 256 + threadIdx.x;
    if (idx >= n * 8) return;
    int r = idx >> 3, k = idx & 7;
    unsigned U = *U1p;
    if ((unsigned)r >= U) {
        float4 z = make_float4(0.f, 0.f, 0.f, 0.f);
        ((float4*)outMax)[idx] = z;
        if (k == 0) ((float4*)outCoord)[r] = z;
    } else if (flags[r]) {
        unsigned* u4 = (unsigned*)outMax + (size_t)idx * 4;
        float* f4 = outMax + (size_t)idx * 4;
#pragma unroll
        for (int o = 0; o < 4; ++o) f4[o] = o2f(u4[o]);
    }
}

// ---------------- host launch ----------------

extern "C" void kernel_launch(void* const* d_in, const int* in_sizes, int n_in,
                              void* d_out, int out_size, void* d_ws, size_t ws_size,
                              hipStream_t stream) {
    const float4* pc = (const float4*)d_in[0];
    const int* ind   = (const int*)d_in[1];
    const float* w05 = (const float*)d_in[2];
    const float* b05 = (const float*)d_in[3];
    const float* ww05 = (const float*)d_in[4];
    const float* wb05 = (const float*)d_in[5];
    const float* w1  = (const float*)d_in[6];
    const float* b1  = (const float*)d_in[7];
    const float* ww1 = (const float*)d_in[8];
    const float* wb1 = (const float*)d_in[9];
    const float* am_w = (const float*)d_in[10];
    const float* am_b = (const float*)d_in[11];
    const float* at_w = (const float*)d_in[12];
    const float* at_b = (const float*)d_in[13];
    const float* af_w = (const float*)d_in[14];
    const float* af_b = (const float*)d_in[15];

    int n = in_sizes[0] / 4;
    int B = in_sizes[1] - 1;

    int nW05 = B * (512 * 512 * 64 / 32);
    int nW1  = B * (256 * 256 * 32 / 32);
    int nB05 = (nW05 + 2047) / 2048;
    int nB1  = (nW1 + 2047) / 2048;
    int nCh  = (n + 2047) / 2048;

    size_t off = 0;
    char* base = (char*)d_ws;
    auto take = [&](size_t bytes) -> char* {
        char* p = base + off;
        off = (off + bytes + 255) & ~(size_t)255;
        return p;
    };

    // zero-init group (single contiguous memset)
    unsigned* mask05 = (unsigned*)take((size_t)nW05 * 4);
    unsigned* mask1  = (unsigned*)take((size_t)nW1 * 4);
    unsigned* cnt05  = (unsigned*)take((size_t)n * 4);
    unsigned* cnt1   = (unsigned*)take((size_t)n * 4);
    unsigned char* flags = (unsigned char*)take((size_t)n);
    size_t zeroBytes = off;

    unsigned* wp05   = (unsigned*)take((size_t)nW05 * 4);
    unsigned* wp1    = (unsigned*)take((size_t)nW1 * 4);
    unsigned* inv05  = (unsigned*)take((size_t)n * 4);
    unsigned* inv1   = (unsigned*)take((size_t)n * 4);
    unsigned* slot05 = (unsigned*)take((size_t)n * 4);
    unsigned* slot1  = (unsigned*)take((size_t)n * 4);
    unsigned* start05 = (unsigned*)take((size_t)n * 4);
    unsigned* start1  = (unsigned*)take((size_t)n * 4);
    uint4*    recA05  = (uint4*)take((size_t)n * 32);  // {p | r05,-,-,-}
    uint4*    recA1   = (uint4*)take((size_t)n * 32);  // {p | r1,r05,meta,-}
    float4*   mean05  = (float4*)take((size_t)n * 16);
    float4*   mean1   = (float4*)take((size_t)n * 16);
    unsigned short* mx05 = (unsigned short*)take((size_t)n * 32);  // bf16 [n][16]
    unsigned short* mx1  = (unsigned short*)take((size_t)n * 32);
    float*    atT     = (float*)take((size_t)2048 * 4);  // at_w transposed [64][32]
    float*    afT     = (float*)take((size_t)1024 * 4);  // af_w transposed [32][32]
    float*    amT     = (float*)take((size_t)192 * 4);   // am_w transposed [6][32]
    unsigned* bsum05  = (unsigned*)take((size_t)nB05 * 4);
    unsigned* bpref05 = (unsigned*)take((size_t)nB05 * 4);
    unsigned* bsum1   = (unsigned*)take((size_t)nB1 * 4);
    unsigned* bpref1  = (unsigned*)take((size_t)nB1 * 4);
    unsigned* bsC05   = (unsigned*)take((size_t)nCh * 4);
    unsigned* bpC05   = (unsigned*)take((size_t)nCh * 4);
    unsigned* bsC1    = (unsigned*)take((size_t)nCh * 4);
    unsigned* bpC1    = (unsigned*)take((size_t)nCh * 4);
    unsigned* U1p     = (unsigned*)take(4);
    size_t total = off;

    if (ws_size < total) {
        fprintf(stderr, "kernel_launch: ws too small (%zu < %zu)\n", ws_size, total);
        return;
    }

    float* outMaxF = (float*)d_out;                      // [n,32]
    float* outCoord = (float*)d_out + (size_t)n * 32;    // [n,4]
    float* outInv = (float*)d_out + (size_t)n * 36;      // [n]

    hipMemsetAsync(d_ws, 0, zeroBytes, stream);

    int gpts = (n + 255) / 256;
    int nbb  = (gpts + 255) / 256;
    // weight transposes (no dependencies; overlaps the rest)
    k_wtr<<<13, 256, 0, stream>>>(at_w, af_w, am_w, atT, afT, amT);
    // unique-rank machinery (both scales per launch)
    k_bits<<<gpts, 256, 0, stream>>>(pc, ind, B, n, mask05, mask1);
    k_chunk2<<<nB05 + nB1, 256, 0, stream>>>(mask05, bsum05, nW05, nB05,
                                             mask1, bsum1, nW1);
    k_scan2<<<2, 1024, 0, stream>>>(bsum05, bpref05, nullptr, nB05,
                                    bsum1, bpref1, U1p, nB1);
    k_wpref2<<<nB05 + nB1, 256, 0, stream>>>(mask05, bpref05, wp05, nW05, nB05,
                                             mask1, bpref1, wp1, nW1);
    // ranks + counts + slots (one atomic per point per scale)
    k_rank<<<gpts, 256, 0, stream>>>(pc, ind, B, n, mask05, wp05, mask1, wp1,
                                     inv05, inv1, cnt05, cnt1, slot05, slot1,
                                     outCoord, outInv);
    // CSR starts
    k_chunku2<<<2 * nCh, 256, 0, stream>>>(cnt05, bsC05, cnt1, bsC1, n, nCh);
    k_scan2<<<2, 1024, 0, stream>>>(bsC05, bpC05, nullptr, nCh,
                                    bsC1, bpC1, nullptr, nCh);
    k_eprefu2<<<2 * nCh, 256, 0, stream>>>(cnt05, bpC05, start05,
                                           cnt1, bpC1, start1, n, nCh);
    // counting-sort scatter of 32B point records (plain stores)
    k_slot<<<gpts, 256, 0, stream>>>(pc, inv05, inv1, slot05, slot1,
                                     start05, start1, cnt1, recA05, recA1, n);
    // per-voxel means (both scales) + boundary flags/binit (third range)
    k_segmean2<<<2 * gpts + nbb, 256, 0, stream>>>(recA05, start05, cnt05, mean05,
                                                   recA1, start1, cnt1, mean1,
                                                   flags, (unsigned*)outMaxF, n, gpts);
    // per-voxel mx (bf16), both scales in one launch
    k_segmx2<<<2 * gpts, 256, 0, stream>>>(recA05, start05, cnt05, mean05,
                                           w05, b05, ww05, wb05, mx05,
                                           recA1, start1, cnt1, mean1,
                                           w1, b1, ww1, wb1, mx1, n, gpts);
    // fused pipeline + two-phase segmented max (float2-paired matvecs)
    k_val<<<gpts, 256, 0, stream>>>(recA1,
                                    mean05, mx05, mean1, mx1,
                                    w05, b05, ww05, wb05, w1, b1, ww1, wb1,
                                    amT, am_b, atT, at_b, afT, af_b,
                                    outMaxF, n);
    // untransform boundary rows + zero pad rows (coalesced, float4/thread)
    k_finrow<<<(n * 8 + 255) / 256, 256, 0, stream>>>(outMaxF, outCoord, flags, U1p, n);

    (void)n_in; (void)out_size;
}